// Round 8
// baseline (1486.270 us; speedup 1.0000x reference)
//
#include <hip/hip_runtime.h>
#include <math.h>

// Problem constants (z: [2,16384,256] f32, emb: [8192,256] f32)
#define D_DIM 256
#define NE    8192
#define M_TOT 32768L

// Output layout (f32 elements): z_q_st | loss | idx | age | usage
#define O_LOSS  8388608L
#define O_IDX   8388609L
#define O_AGE   8421377L
#define O_USAGE 8429569L

typedef __attribute__((ext_vector_type(8))) short bf16x8;
typedef __attribute__((ext_vector_type(4))) short bf16x4;
typedef __attribute__((ext_vector_type(4))) float f32x4;

__device__ __forceinline__ short f2bf(float f) {   // RNE f32 -> bf16 bits
  unsigned u = __float_as_uint(f);
  u += 0x7FFFu + ((u >> 16) & 1u);
  return (short)(u >> 16);
}
__device__ __forceinline__ float bf2f(short s) {
  return __uint_as_float(((unsigned)(unsigned short)s) << 16);
}

// ---------------------------------------------------------------------------
// Kernel 1: f32 row norms (f64-accumulated, f32-rounded) for z and emb,
// init age/usage defaults, zero loss + flag counter.
__global__ __launch_bounds__(256) void vq_prep(
    const float* __restrict__ z, const float* __restrict__ emb,
    const float* __restrict__ code_age, const float* __restrict__ code_usage,
    float* __restrict__ out, float* __restrict__ zzf, float* __restrict__ enf,
    int* __restrict__ cnt) {
  int t = blockIdx.x * 256 + threadIdx.x;  // 0..32767
  {
    const float4* row = reinterpret_cast<const float4*>(z + (size_t)t * D_DIM);
    double s = 0.0;
#pragma unroll
    for (int q = 0; q < D_DIM / 4; ++q) {
      float4 v = row[q];
      s = fma((double)v.x, (double)v.x, s);
      s = fma((double)v.y, (double)v.y, s);
      s = fma((double)v.z, (double)v.z, s);
      s = fma((double)v.w, (double)v.w, s);
    }
    zzf[t] = (float)s;
  }
  if (t < NE) {
    const float4* row = reinterpret_cast<const float4*>(emb + (size_t)t * D_DIM);
    double s = 0.0;
#pragma unroll
    for (int q = 0; q < D_DIM / 4; ++q) {
      float4 v = row[q];
      s = fma((double)v.x, (double)v.x, s);
      s = fma((double)v.y, (double)v.y, s);
      s = fma((double)v.z, (double)v.z, s);
      s = fma((double)v.w, (double)v.w, s);
    }
    enf[t] = (float)s;
    out[O_AGE + t] = code_age[t] + 1.0f;
    out[O_USAGE + t] = code_usage[t];
    if (t == 0) { out[O_LOSS] = 0.0f; *cnt = 0; }
  }
}

// ---------------------------------------------------------------------------
// Kernel 2: split-bf16 MFMA argmin pass.
// 256 blocks x 512 threads (8 waves: 4 row-groups x 2 col-groups).
// Block tile 128 rows x full 8192 codes (jt loop). Wave tile 32x64.
// z split (hi+lo bf16) held in registers for the whole code loop; emb slice
// split into LDS per k-step. ze = zl*eh + zh*eh + zh*el (3 MFMA, f32 acc).
// Epilogue: dv = fl(fl(zz-2*ze)+en), per-row top-2, lowest-index ties.
#define LDK 40   // shorts per LDS row (32 + 8 pad) -> 80 B stride, 2-way banks

__global__ __launch_bounds__(512, 2) void vq_argmin_mfma(
    const float* __restrict__ z, const float* __restrict__ emb,
    const float* __restrict__ zzf, const float* __restrict__ enf,
    float* __restrict__ pv1, float* __restrict__ pv2, int* __restrict__ pj1) {
  __shared__ short th[128 * LDK];
  __shared__ short tl[128 * LDK];

  const int tid = threadIdx.x;
  const int lane = tid & 63;
  const int wave = tid >> 6;        // 0..7
  const int wr = wave >> 1;         // row group 0..3
  const int wc = wave & 1;          // col group 0..1
  const int lrow = lane & 15;
  const int lq = lane >> 4;         // 0..3
  const size_t row0 = (size_t)blockIdx.x * 128;

  const int srow = tid >> 2;        // staging: 0..127
  const int skq = (tid & 3) * 8;    // staging k offset 0,8,16,24

  // ---- phase 1: split A (z rows) into register fragments, full K ----
  bf16x8 afh[2][8], afl[2][8];
#pragma unroll
  for (int ks = 0; ks < 8; ++ks) {
    __syncthreads();
    {
      const float* src = z + (row0 + srow) * (size_t)D_DIM + ks * 32 + skq;
      float4 v0 = *reinterpret_cast<const float4*>(src);
      float4 v1 = *reinterpret_cast<const float4*>(src + 4);
      float s[8] = {v0.x, v0.y, v0.z, v0.w, v1.x, v1.y, v1.z, v1.w};
      short h[8], l[8];
#pragma unroll
      for (int i = 0; i < 8; ++i) {
        h[i] = f2bf(s[i]);
        l[i] = f2bf(s[i] - bf2f(h[i]));
      }
      bf16x4 hv0 = {h[0], h[1], h[2], h[3]}, hv1 = {h[4], h[5], h[6], h[7]};
      bf16x4 lv0 = {l[0], l[1], l[2], l[3]}, lv1 = {l[4], l[5], l[6], l[7]};
      *reinterpret_cast<bf16x4*>(&th[srow * LDK + skq]) = hv0;
      *reinterpret_cast<bf16x4*>(&th[srow * LDK + skq + 4]) = hv1;
      *reinterpret_cast<bf16x4*>(&tl[srow * LDK + skq]) = lv0;
      *reinterpret_cast<bf16x4*>(&tl[srow * LDK + skq + 4]) = lv1;
    }
    __syncthreads();
#pragma unroll
    for (int rt = 0; rt < 2; ++rt) {
      int r = wr * 32 + rt * 16 + lrow;
      afh[rt][ks] = *reinterpret_cast<const bf16x8*>(&th[r * LDK + lq * 8]);
      afl[rt][ks] = *reinterpret_cast<const bf16x8*>(&tl[r * LDK + lq * 8]);
    }
  }

  // per-lane row slots: slot s=rt*4+rr -> row row0 + wr*32 + rt*16 + lq*4 + rr
  float zrow2[8];
#pragma unroll
  for (int rt = 0; rt < 2; ++rt)
#pragma unroll
    for (int rr = 0; rr < 4; ++rr)
      zrow2[rt * 4 + rr] = zzf[row0 + wr * 32 + rt * 16 + lq * 4 + rr];

  float bv1[8], bv2[8];
  int bj1[8];
#pragma unroll
  for (int s = 0; s < 8; ++s) { bv1[s] = INFINITY; bv2[s] = INFINITY; bj1[s] = 0; }

  // ---- phase 2: loop over 64 code tiles of 128 ----
  for (int jt0 = 0; jt0 < NE; jt0 += 128) {
    float enq[4];
#pragma unroll
    for (int ct = 0; ct < 4; ++ct) enq[ct] = enf[jt0 + wc * 64 + ct * 16 + lrow];

    f32x4 acc[2][4];
#pragma unroll
    for (int rt = 0; rt < 2; ++rt)
#pragma unroll
      for (int ct = 0; ct < 4; ++ct) acc[rt][ct] = (f32x4){0.f, 0.f, 0.f, 0.f};

#pragma unroll
    for (int ks = 0; ks < 8; ++ks) {
      __syncthreads();
      {
        const float* src = emb + (size_t)(jt0 + srow) * D_DIM + ks * 32 + skq;
        float4 v0 = *reinterpret_cast<const float4*>(src);
        float4 v1 = *reinterpret_cast<const float4*>(src + 4);
        float s[8] = {v0.x, v0.y, v0.z, v0.w, v1.x, v1.y, v1.z, v1.w};
        short h[8], l[8];
#pragma unroll
        for (int i = 0; i < 8; ++i) {
          h[i] = f2bf(s[i]);
          l[i] = f2bf(s[i] - bf2f(h[i]));
        }
        bf16x4 hv0 = {h[0], h[1], h[2], h[3]}, hv1 = {h[4], h[5], h[6], h[7]};
        bf16x4 lv0 = {l[0], l[1], l[2], l[3]}, lv1 = {l[4], l[5], l[6], l[7]};
        *reinterpret_cast<bf16x4*>(&th[srow * LDK + skq]) = hv0;
        *reinterpret_cast<bf16x4*>(&th[srow * LDK + skq + 4]) = hv1;
        *reinterpret_cast<bf16x4*>(&tl[srow * LDK + skq]) = lv0;
        *reinterpret_cast<bf16x4*>(&tl[srow * LDK + skq + 4]) = lv1;
      }
      __syncthreads();
      bf16x8 bf[4];
#pragma unroll
      for (int ct = 0; ct < 4; ++ct) {
        int c = wc * 64 + ct * 16 + lrow;
        bf[ct] = *reinterpret_cast<const bf16x8*>(&th[c * LDK + lq * 8]);
      }
#pragma unroll
      for (int rt = 0; rt < 2; ++rt)
#pragma unroll
        for (int ct = 0; ct < 4; ++ct) {
          acc[rt][ct] = __builtin_amdgcn_mfma_f32_16x16x32_bf16(
              afl[rt][ks], bf[ct], acc[rt][ct], 0, 0, 0);   // zl*eh
          acc[rt][ct] = __builtin_amdgcn_mfma_f32_16x16x32_bf16(
              afh[rt][ks], bf[ct], acc[rt][ct], 0, 0, 0);   // zh*eh
        }
#pragma unroll
      for (int ct = 0; ct < 4; ++ct) {
        int c = wc * 64 + ct * 16 + lrow;
        bf[ct] = *reinterpret_cast<const bf16x8*>(&tl[c * LDK + lq * 8]);
      }
#pragma unroll
      for (int rt = 0; rt < 2; ++rt)
#pragma unroll
        for (int ct = 0; ct < 4; ++ct)
          acc[rt][ct] = __builtin_amdgcn_mfma_f32_16x16x32_bf16(
              afh[rt][ks], bf[ct], acc[rt][ct], 0, 0, 0);   // zh*el
    }

    // epilogue: reference f32 chain; ct ascending + jt ascending + strict <
    // -> lowest index on ties
#pragma unroll
    for (int ct = 0; ct < 4; ++ct) {
      int gj = jt0 + wc * 64 + ct * 16 + lrow;
      float ef = enq[ct];
#pragma unroll
      for (int rt = 0; rt < 2; ++rt)
#pragma unroll
        for (int rr = 0; rr < 4; ++rr) {
          int s = rt * 4 + rr;
          float t = zrow2[s] - 2.0f * acc[rt][ct][rr];
          float dv = t + ef;
          if (dv < bv1[s]) {
            bv2[s] = bv1[s]; bv1[s] = dv; bj1[s] = gj;
          } else if (dv < bv2[s]) {
            bv2[s] = dv;
          }
        }
    }
  }

  // reduce top-2 across the 16 code-lanes (lrow) of each lane quarter
#pragma unroll
  for (int m = 1; m < 16; m <<= 1) {
#pragma unroll
    for (int s = 0; s < 8; ++s) {
      float ov1 = __shfl_xor(bv1[s], m, 16);
      float ov2 = __shfl_xor(bv2[s], m, 16);
      int oj1 = __shfl_xor(bj1[s], m, 16);
      if (ov1 < bv1[s] || (ov1 == bv1[s] && oj1 < bj1[s])) {
        bv2[s] = fminf(bv1[s], ov2);
        bv1[s] = ov1; bj1[s] = oj1;
      } else {
        bv2[s] = fminf(bv2[s], ov1);
      }
    }
  }
  if (lrow == 0) {
#pragma unroll
    for (int s = 0; s < 8; ++s) {
      size_t grow = row0 + wr * 32 + (s >> 2) * 16 + lq * 4 + (s & 3);
      size_t o = (size_t)wc * M_TOT + grow;
      pv1[o] = bv1[s]; pv2[o] = bv2[s]; pj1[o] = bj1[s];
    }
  }
}

// ---------------------------------------------------------------------------
// Kernel 3: fold the 2 col-split partial top-2s per row; flag ambiguous rows.
// Margin: 2*ulp(dv grid) covers ours-vs-ref quantization; 1e-5 slack covers
// worst-coherent split-bf16 ze error (<=4.2e-6 in dv) with 2x headroom.
#define MSPLIT 2

__global__ __launch_bounds__(256) void vq_merge(
    const float* __restrict__ pv1, const float* __restrict__ pv2,
    const int* __restrict__ pj1, int* __restrict__ idx_ws,
    int* __restrict__ cnt, int* __restrict__ flagged) {
  int m = blockIdx.x * 256 + threadIdx.x;
  if (m >= M_TOT) return;
  float v1 = INFINITY, v2 = INFINITY;
  int j1 = 0;
#pragma unroll
  for (int s = 0; s < MSPLIT; ++s) {
    float a1 = pv1[(size_t)s * M_TOT + m];
    float a2 = pv2[(size_t)s * M_TOT + m];
    int aj = pj1[(size_t)s * M_TOT + m];
    if (a1 < v1 || (a1 == v1 && aj < j1)) {
      v2 = fminf(v1, a2); v1 = a1; j1 = aj;
    } else {
      v2 = fminf(v2, a1);
    }
  }
  idx_ws[m] = j1;
  float u = ldexpf(1.0f, ilogbf(v2) - 23);
  if (v2 - v1 <= 2.0f * u + 1e-5f) {
    int p = atomicAdd(cnt, 1);
    flagged[p] = m;
  }
}

// ---------------------------------------------------------------------------
// Kernel 4: exact refine for flagged rows. 4 rows/block, full 8192-code scan,
// f64 dot (correctly-rounded f32 ze), reference f32 chain, lowest-index ties.
#define RROWS 4

__global__ __launch_bounds__(256) void vq_refine(
    const float* __restrict__ z, const float* __restrict__ emb,
    const float* __restrict__ zzf, const float* __restrict__ enf,
    int* __restrict__ idx_ws, const int* __restrict__ cnt,
    const int* __restrict__ flagged) {
  __shared__ float zs[RROWS][D_DIM + 4];
  __shared__ float rzz[RROWS];
  __shared__ float rv[RROWS][256];
  __shared__ int rj[RROWS][256];

  const int tid = threadIdx.x;
  int n = *cnt;
  if (n > (int)M_TOT) n = (int)M_TOT;

  for (int base = blockIdx.x * RROWS; base < n; base += gridDim.x * RROWS) {
    int nb = n - base; if (nb > RROWS) nb = RROWS;
    __syncthreads();
    {
      int r = tid >> 6;               // 4 rows x 64 threads
      int kk = (tid & 63) * 4;        // one float4 each
      if (r < nb) {
        size_t m = (size_t)flagged[base + r];
        *reinterpret_cast<float4*>(&zs[r][kk]) =
            *reinterpret_cast<const float4*>(z + m * D_DIM + kk);
      }
      if (tid < nb) rzz[tid] = zzf[flagged[base + tid]];
    }
    __syncthreads();

    float bv[RROWS]; int bj[RROWS];
#pragma unroll
    for (int r = 0; r < RROWS; ++r) { bv[r] = INFINITY; bj[r] = 0; }

    for (int j = tid; j < NE; j += 256) {
      const float4* er = reinterpret_cast<const float4*>(emb + (size_t)j * D_DIM);
      double acc[RROWS];
#pragma unroll
      for (int r = 0; r < RROWS; ++r) acc[r] = 0.0;
      for (int k4 = 0; k4 < D_DIM / 4; ++k4) {
        float4 ev = er[k4];
        double e0 = ev.x, e1 = ev.y, e2 = ev.z, e3 = ev.w;
#pragma unroll
        for (int r = 0; r < RROWS; ++r) {
          float4 zv = *reinterpret_cast<const float4*>(&zs[r][k4 * 4]);
          double a = acc[r];
          a = fma((double)zv.x, e0, a);
          a = fma((double)zv.y, e1, a);
          a = fma((double)zv.z, e2, a);
          a = fma((double)zv.w, e3, a);
          acc[r] = a;
        }
      }
      float ef = enf[j];
#pragma unroll
      for (int r = 0; r < RROWS; ++r) {
        float zef = (float)acc[r];          // correctly-rounded f32(ze)
        float t = rzz[r] - 2.0f * zef;
        float dv = t + ef;
        if (dv < bv[r]) { bv[r] = dv; bj[r] = j; }   // j ascending
      }
    }
#pragma unroll
    for (int r = 0; r < RROWS; ++r) { rv[r][tid] = bv[r]; rj[r][tid] = bj[r]; }
    __syncthreads();
    for (int s = 128; s > 0; s >>= 1) {
      if (tid < s) {
#pragma unroll
        for (int r = 0; r < RROWS; ++r) {
          float ov = rv[r][tid + s]; int oj = rj[r][tid + s];
          if (ov < rv[r][tid] || (ov == rv[r][tid] && oj < rj[r][tid])) {
            rv[r][tid] = ov; rj[r][tid] = oj;
          }
        }
      }
      __syncthreads();
    }
    if (tid < nb) idx_ws[flagged[base + tid]] = rj[tid][0];
  }
}

// ---------------------------------------------------------------------------
// Kernel 5: idx (as float), age reset, usage histogram — after refine.
__global__ __launch_bounds__(256) void vq_scatter(
    const int* __restrict__ idx_ws, float* __restrict__ out) {
  int m = blockIdx.x * 256 + threadIdx.x;
  if (m >= M_TOT) return;
  int j = idx_ws[m];
  out[O_IDX + m] = (float)j;
  out[O_AGE + j] = 0.0f;            // benign race: all write 0
  atomicAdd(&out[O_USAGE + j], 1.0f);
}

// ---------------------------------------------------------------------------
// Kernel 6: z_q_st = z + (q - z) (mimics ref rounding), loss accumulation
// (one atomic per block via LDS wave-partials).
__global__ __launch_bounds__(256) void vq_gather(
    const float* __restrict__ z, const float* __restrict__ emb,
    const int* __restrict__ idx_ws, float* __restrict__ out) {
  __shared__ float lsum[4];
  size_t e4 = (size_t)blockIdx.x * 256 + threadIdx.x;  // float4 index
  size_t m = e4 >> 6;       // / (D/4)
  int dq = (int)(e4 & 63);
  int j = idx_ws[m];
  float4 q = *reinterpret_cast<const float4*>(emb + (size_t)j * D_DIM + dq * 4);
  float4 zv = *reinterpret_cast<const float4*>(z + e4 * 4);
  float dx = q.x - zv.x, dy = q.y - zv.y, dz = q.z - zv.z, dw = q.w - zv.w;
  float4 o;
  o.x = zv.x + dx; o.y = zv.y + dy; o.z = zv.z + dz; o.w = zv.w + dw;
  *reinterpret_cast<float4*>(out + e4 * 4) = o;
  float ls = dx * dx + dy * dy + dz * dz + dw * dw;
#pragma unroll
  for (int off = 32; off > 0; off >>= 1) ls += __shfl_down(ls, off, 64);
  if ((threadIdx.x & 63) == 0) lsum[threadIdx.x >> 6] = ls;
  __syncthreads();
  if (threadIdx.x == 0)
    atomicAdd(out + O_LOSS,
              (lsum[0] + lsum[1] + lsum[2] + lsum[3]) * (1.25f / 8388608.f));
}

// ---------------------------------------------------------------------------
// ws layout (f32 units): zzf[32768] | enf[8192] | idx_ws[32768] | cnt |
//   flagged[32768] | pv1[2*32768] | pv2[2*32768] | pj1[2*32768]  (~1.2 MB)
extern "C" void kernel_launch(void* const* d_in, const int* in_sizes, int n_in,
                              void* d_out, int out_size, void* d_ws, size_t ws_size,
                              hipStream_t stream) {
  const float* z = (const float*)d_in[0];
  const float* emb = (const float*)d_in[1];
  const float* code_age = (const float*)d_in[2];
  const float* code_usage = (const float*)d_in[3];
  float* out = (float*)d_out;

  float* zzf = (float*)d_ws;
  float* enf = zzf + M_TOT;
  int* idx_ws = (int*)(enf + NE);
  int* cnt = idx_ws + M_TOT;
  int* flagged = cnt + 1;
  float* pv1 = (float*)(flagged + M_TOT);
  float* pv2 = pv1 + MSPLIT * M_TOT;
  int* pj1 = (int*)(pv2 + MSPLIT * M_TOT);

  hipLaunchKernelGGL(vq_prep, dim3(M_TOT / 256), dim3(256), 0, stream,
                     z, emb, code_age, code_usage, out, zzf, enf, cnt);
  hipLaunchKernelGGL(vq_argmin_mfma, dim3(M_TOT / 128), dim3(512), 0, stream,
                     z, emb, zzf, enf, pv1, pv2, pj1);
  hipLaunchKernelGGL(vq_merge, dim3(M_TOT / 256), dim3(256), 0, stream,
                     pv1, pv2, pj1, idx_ws, cnt, flagged);
  hipLaunchKernelGGL(vq_refine, dim3(2048), dim3(256), 0, stream,
                     z, emb, zzf, enf, idx_ws, cnt, flagged);
  hipLaunchKernelGGL(vq_scatter, dim3(M_TOT / 256), dim3(256), 0, stream,
                     idx_ws, out);
  hipLaunchKernelGGL(vq_gather, dim3((M_TOT * (D_DIM / 4)) / 256), dim3(256), 0, stream,
                     z, emb, idx_ws, out);
}

// Round 9
// 1354.250 us; speedup vs baseline: 1.0975x; 1.0975x over previous
//
#include <hip/hip_runtime.h>
#include <math.h>

// Problem constants (z: [2,16384,256] f32, emb: [8192,256] f32)
#define D_DIM 256
#define NE    8192
#define M_TOT 32768L

// Output layout (f32 elements): z_q_st | loss | idx | age | usage
#define O_LOSS  8388608L
#define O_IDX   8388609L
#define O_AGE   8421377L
#define O_USAGE 8429569L

typedef __attribute__((ext_vector_type(8))) short bf16x8;
typedef __attribute__((ext_vector_type(4))) short bf16x4;
typedef __attribute__((ext_vector_type(4))) float f32x4;

__device__ __forceinline__ short f2bf(float f) {   // RNE f32 -> bf16 bits
  unsigned u = __float_as_uint(f);
  u += 0x7FFFu + ((u >> 16) & 1u);
  return (short)(u >> 16);
}
__device__ __forceinline__ float bf2f(short s) {
  return __uint_as_float(((unsigned)(unsigned short)s) << 16);
}

// ---------------------------------------------------------------------------
// Kernel 1: f32 row norms (f64-accumulated, f32-rounded) for z and emb,
// init age/usage defaults, zero loss + flag counter.
__global__ __launch_bounds__(256) void vq_prep(
    const float* __restrict__ z, const float* __restrict__ emb,
    const float* __restrict__ code_age, const float* __restrict__ code_usage,
    float* __restrict__ out, float* __restrict__ zzf, float* __restrict__ enf,
    int* __restrict__ cnt) {
  int t = blockIdx.x * 256 + threadIdx.x;  // 0..32767
  {
    const float4* row = reinterpret_cast<const float4*>(z + (size_t)t * D_DIM);
    double s = 0.0;
#pragma unroll
    for (int q = 0; q < D_DIM / 4; ++q) {
      float4 v = row[q];
      s = fma((double)v.x, (double)v.x, s);
      s = fma((double)v.y, (double)v.y, s);
      s = fma((double)v.z, (double)v.z, s);
      s = fma((double)v.w, (double)v.w, s);
    }
    zzf[t] = (float)s;
  }
  if (t < NE) {
    const float4* row = reinterpret_cast<const float4*>(emb + (size_t)t * D_DIM);
    double s = 0.0;
#pragma unroll
    for (int q = 0; q < D_DIM / 4; ++q) {
      float4 v = row[q];
      s = fma((double)v.x, (double)v.x, s);
      s = fma((double)v.y, (double)v.y, s);
      s = fma((double)v.z, (double)v.z, s);
      s = fma((double)v.w, (double)v.w, s);
    }
    enf[t] = (float)s;
    out[O_AGE + t] = code_age[t] + 1.0f;
    out[O_USAGE + t] = code_usage[t];
    if (t == 0) { out[O_LOSS] = 0.0f; *cnt = 0; }
  }
}

// ---------------------------------------------------------------------------
// Kernel 1b: split emb into bf16 hi/lo planes (row-major) once.
__global__ __launch_bounds__(256) void vq_split(
    const float* __restrict__ emb, short* __restrict__ emb_h,
    short* __restrict__ emb_l) {
  int e4 = blockIdx.x * 256 + threadIdx.x;      // float4 index over 8192*64
  float4 v = reinterpret_cast<const float4*>(emb)[e4];
  float s[4] = {v.x, v.y, v.z, v.w};
  short h[4], l[4];
#pragma unroll
  for (int i = 0; i < 4; ++i) {
    h[i] = f2bf(s[i]);
    l[i] = f2bf(s[i] - bf2f(h[i]));
  }
  *reinterpret_cast<bf16x4*>(emb_h + (size_t)e4 * 4) = (bf16x4){h[0], h[1], h[2], h[3]};
  *reinterpret_cast<bf16x4*>(emb_l + (size_t)e4 * 4) = (bf16x4){l[0], l[1], l[2], l[3]};
}

// ---------------------------------------------------------------------------
// Kernel 2: split-bf16 MFMA argmin pass.
// 256 blocks x 512 threads (8 waves: 4 row-groups x 2 col-groups).
// Block tile 128 rows x full 8192 codes (jt loop). Wave tile 32x64.
// z split held in registers for the whole code loop. PRESPLIT=1: emb hi/lo
// staged straight from precomputed bf16 planes with 1-step reg prefetch;
// PRESPLIT=0 (small-ws fallback): in-loop f32->bf16 split as in round 8.
// ze = zl*eh + zh*eh + zh*el (3 MFMA, f32 acc).
// Epilogue: dv = fl(fl(zz-2*ze)+en), per-row top-2, lowest-index ties.
#define LDK 40   // shorts per LDS row (32 + 8 pad) -> 80 B stride, 2-way banks

template <int PRESPLIT>
__global__ __launch_bounds__(512, 2) void vq_argmin_mfma(
    const float* __restrict__ z, const float* __restrict__ emb,
    const short* __restrict__ emb_h, const short* __restrict__ emb_l,
    const float* __restrict__ zzf, const float* __restrict__ enf,
    float* __restrict__ pv1, float* __restrict__ pv2, int* __restrict__ pj1) {
  __shared__ short th[128 * LDK];
  __shared__ short tl[128 * LDK];

  const int tid = threadIdx.x;
  const int lane = tid & 63;
  const int wave = tid >> 6;        // 0..7
  const int wr = wave >> 1;         // row group 0..3
  const int wc = wave & 1;          // col group 0..1
  const int lrow = lane & 15;
  const int lq = lane >> 4;         // 0..3
  const size_t row0 = (size_t)blockIdx.x * 128;

  const int srow = tid >> 2;        // staging: 0..127
  const int skq = (tid & 3) * 8;    // staging k offset (shorts): 0,8,16,24

  // ---- phase 1: split A (z rows) into register fragments, full K ----
  bf16x8 afh[2][8], afl[2][8];
#pragma unroll
  for (int ks = 0; ks < 8; ++ks) {
    __syncthreads();
    {
      const float* src = z + (row0 + srow) * (size_t)D_DIM + ks * 32 + skq;
      float4 v0 = *reinterpret_cast<const float4*>(src);
      float4 v1 = *reinterpret_cast<const float4*>(src + 4);
      float s[8] = {v0.x, v0.y, v0.z, v0.w, v1.x, v1.y, v1.z, v1.w};
      short h[8], l[8];
#pragma unroll
      for (int i = 0; i < 8; ++i) {
        h[i] = f2bf(s[i]);
        l[i] = f2bf(s[i] - bf2f(h[i]));
      }
      *reinterpret_cast<bf16x4*>(&th[srow * LDK + skq]) = (bf16x4){h[0], h[1], h[2], h[3]};
      *reinterpret_cast<bf16x4*>(&th[srow * LDK + skq + 4]) = (bf16x4){h[4], h[5], h[6], h[7]};
      *reinterpret_cast<bf16x4*>(&tl[srow * LDK + skq]) = (bf16x4){l[0], l[1], l[2], l[3]};
      *reinterpret_cast<bf16x4*>(&tl[srow * LDK + skq + 4]) = (bf16x4){l[4], l[5], l[6], l[7]};
    }
    __syncthreads();
#pragma unroll
    for (int rt = 0; rt < 2; ++rt) {
      int r = wr * 32 + rt * 16 + lrow;
      afh[rt][ks] = *reinterpret_cast<const bf16x8*>(&th[r * LDK + lq * 8]);
      afl[rt][ks] = *reinterpret_cast<const bf16x8*>(&tl[r * LDK + lq * 8]);
    }
  }

  // per-lane row slots: slot s=rt*4+rr -> row row0 + wr*32 + rt*16 + lq*4 + rr
  float zrow2[8];
#pragma unroll
  for (int rt = 0; rt < 2; ++rt)
#pragma unroll
    for (int rr = 0; rr < 4; ++rr)
      zrow2[rt * 4 + rr] = zzf[row0 + wr * 32 + rt * 16 + lq * 4 + rr];

  float bv1[8], bv2[8];
  int bj1[8];
#pragma unroll
  for (int s = 0; s < 8; ++s) { bv1[s] = INFINITY; bv2[s] = INFINITY; bj1[s] = 0; }

  // ---- phase 2: loop over 64 code tiles of 128 ----
  for (int jt0 = 0; jt0 < NE; jt0 += 128) {
    float enq[4];
#pragma unroll
    for (int ct = 0; ct < 4; ++ct) enq[ct] = enf[jt0 + wc * 64 + ct * 16 + lrow];

    f32x4 acc[2][4];
#pragma unroll
    for (int rt = 0; rt < 2; ++rt)
#pragma unroll
      for (int ct = 0; ct < 4; ++ct) acc[rt][ct] = (f32x4){0.f, 0.f, 0.f, 0.f};

    bf16x8 ph, pl;
    if (PRESPLIT) {
      ph = *reinterpret_cast<const bf16x8*>(
          emb_h + (size_t)(jt0 + srow) * D_DIM + skq);
      pl = *reinterpret_cast<const bf16x8*>(
          emb_l + (size_t)(jt0 + srow) * D_DIM + skq);
    }

#pragma unroll
    for (int ks = 0; ks < 8; ++ks) {
      __syncthreads();
      if (PRESPLIT) {
        *reinterpret_cast<bf16x8*>(&th[srow * LDK + skq]) = ph;
        *reinterpret_cast<bf16x8*>(&tl[srow * LDK + skq]) = pl;
      } else {
        const float* src = emb + (size_t)(jt0 + srow) * D_DIM + ks * 32 + skq;
        float4 v0 = *reinterpret_cast<const float4*>(src);
        float4 v1 = *reinterpret_cast<const float4*>(src + 4);
        float s[8] = {v0.x, v0.y, v0.z, v0.w, v1.x, v1.y, v1.z, v1.w};
        short h[8], l[8];
#pragma unroll
        for (int i = 0; i < 8; ++i) {
          h[i] = f2bf(s[i]);
          l[i] = f2bf(s[i] - bf2f(h[i]));
        }
        *reinterpret_cast<bf16x4*>(&th[srow * LDK + skq]) = (bf16x4){h[0], h[1], h[2], h[3]};
        *reinterpret_cast<bf16x4*>(&th[srow * LDK + skq + 4]) = (bf16x4){h[4], h[5], h[6], h[7]};
        *reinterpret_cast<bf16x4*>(&tl[srow * LDK + skq]) = (bf16x4){l[0], l[1], l[2], l[3]};
        *reinterpret_cast<bf16x4*>(&tl[srow * LDK + skq + 4]) = (bf16x4){l[4], l[5], l[6], l[7]};
      }
      __syncthreads();
      if (PRESPLIT && ks < 7) {    // prefetch next k-slice under the MFMAs
        ph = *reinterpret_cast<const bf16x8*>(
            emb_h + (size_t)(jt0 + srow) * D_DIM + (ks + 1) * 32 + skq);
        pl = *reinterpret_cast<const bf16x8*>(
            emb_l + (size_t)(jt0 + srow) * D_DIM + (ks + 1) * 32 + skq);
      }
      bf16x8 bf[4];
#pragma unroll
      for (int ct = 0; ct < 4; ++ct) {
        int c = wc * 64 + ct * 16 + lrow;
        bf[ct] = *reinterpret_cast<const bf16x8*>(&th[c * LDK + lq * 8]);
      }
#pragma unroll
      for (int rt = 0; rt < 2; ++rt)
#pragma unroll
        for (int ct = 0; ct < 4; ++ct) {
          acc[rt][ct] = __builtin_amdgcn_mfma_f32_16x16x32_bf16(
              afl[rt][ks], bf[ct], acc[rt][ct], 0, 0, 0);   // zl*eh
          acc[rt][ct] = __builtin_amdgcn_mfma_f32_16x16x32_bf16(
              afh[rt][ks], bf[ct], acc[rt][ct], 0, 0, 0);   // zh*eh
        }
#pragma unroll
      for (int ct = 0; ct < 4; ++ct) {
        int c = wc * 64 + ct * 16 + lrow;
        bf[ct] = *reinterpret_cast<const bf16x8*>(&tl[c * LDK + lq * 8]);
      }
#pragma unroll
      for (int rt = 0; rt < 2; ++rt)
#pragma unroll
        for (int ct = 0; ct < 4; ++ct)
          acc[rt][ct] = __builtin_amdgcn_mfma_f32_16x16x32_bf16(
              afh[rt][ks], bf[ct], acc[rt][ct], 0, 0, 0);   // zh*el
    }

    // epilogue: reference f32 chain; ct ascending + jt ascending + strict <
    // -> lowest index on ties
#pragma unroll
    for (int ct = 0; ct < 4; ++ct) {
      int gj = jt0 + wc * 64 + ct * 16 + lrow;
      float ef = enq[ct];
#pragma unroll
      for (int rt = 0; rt < 2; ++rt)
#pragma unroll
        for (int rr = 0; rr < 4; ++rr) {
          int s = rt * 4 + rr;
          float t = zrow2[s] - 2.0f * acc[rt][ct][rr];
          float dv = t + ef;
          if (dv < bv1[s]) {
            bv2[s] = bv1[s]; bv1[s] = dv; bj1[s] = gj;
          } else if (dv < bv2[s]) {
            bv2[s] = dv;
          }
        }
    }
  }

  // reduce top-2 across the 16 code-lanes (lrow) of each lane quarter
#pragma unroll
  for (int m = 1; m < 16; m <<= 1) {
#pragma unroll
    for (int s = 0; s < 8; ++s) {
      float ov1 = __shfl_xor(bv1[s], m, 16);
      float ov2 = __shfl_xor(bv2[s], m, 16);
      int oj1 = __shfl_xor(bj1[s], m, 16);
      if (ov1 < bv1[s] || (ov1 == bv1[s] && oj1 < bj1[s])) {
        bv2[s] = fminf(bv1[s], ov2);
        bv1[s] = ov1; bj1[s] = oj1;
      } else {
        bv2[s] = fminf(bv2[s], ov1);
      }
    }
  }
  if (lrow == 0) {
#pragma unroll
    for (int s = 0; s < 8; ++s) {
      size_t grow = row0 + wr * 32 + (s >> 2) * 16 + lq * 4 + (s & 3);
      size_t o = (size_t)wc * M_TOT + grow;
      pv1[o] = bv1[s]; pv2[o] = bv2[s]; pj1[o] = bj1[s];
    }
  }
}

// ---------------------------------------------------------------------------
// Kernel 3: fold the 2 col-split partial top-2s per row; flag ambiguous rows
// (also exporting v1 so refine can bound its candidate search).
#define MSPLIT 2

__global__ __launch_bounds__(256) void vq_merge(
    const float* __restrict__ pv1, const float* __restrict__ pv2,
    const int* __restrict__ pj1, int* __restrict__ idx_ws,
    int* __restrict__ cnt, int* __restrict__ flagged,
    float* __restrict__ flagv1) {
  int m = blockIdx.x * 256 + threadIdx.x;
  if (m >= M_TOT) return;
  float v1 = INFINITY, v2 = INFINITY;
  int j1 = 0;
#pragma unroll
  for (int s = 0; s < MSPLIT; ++s) {
    float a1 = pv1[(size_t)s * M_TOT + m];
    float a2 = pv2[(size_t)s * M_TOT + m];
    int aj = pj1[(size_t)s * M_TOT + m];
    if (a1 < v1 || (a1 == v1 && aj < j1)) {
      v2 = fminf(v1, a2); v1 = a1; j1 = aj;
    } else {
      v2 = fminf(v2, a1);
    }
  }
  idx_ws[m] = j1;
  float u = ldexpf(1.0f, ilogbf(v2) - 23);
  if (v2 - v1 <= 2.0f * u + 1e-5f) {
    int p = atomicAdd(cnt, 1);
    flagged[p] = m;
    flagv1[p] = v1;
  }
}

// ---------------------------------------------------------------------------
// Kernel 4: refine flagged rows, two-phase.
//  A) f32-dot scan of all 8192 codes; every j with dv <= v1 + CMARG is a
//     candidate (provably includes the ref argmin: CMARG covers mfma-pass
//     error of v1 plus scan error, each <= ~u+6e-6).
//  B) exact f64 dot for each candidate (typically 2/row) -> ref f32 chain ->
//     min with lowest-index ties. Deterministic overflow fallback: full f64
//     scan for rows whose candidate list exceeds the cap (never in practice).
#define RR 8
#define CAND_CAP 32

__global__ __launch_bounds__(256) void vq_refine(
    const float* __restrict__ z, const float* __restrict__ emb,
    const float* __restrict__ zzf, const float* __restrict__ enf,
    int* __restrict__ idx_ws, const int* __restrict__ cnt,
    const int* __restrict__ flagged, const float* __restrict__ flagv1) {
  __shared__ float zs[RR][D_DIM];
  __shared__ float rzz[RR];
  __shared__ float rthr[RR];
  __shared__ int rowm[RR];
  __shared__ int ncand[RR];
  __shared__ int cj[RR][CAND_CAP];
  __shared__ float cdv[RR][CAND_CAP];
  __shared__ float rv[256];
  __shared__ int rj[256];
  __shared__ int ovf;

  const int tid = threadIdx.x;
  int n = *cnt;
  if (n > (int)M_TOT) n = (int)M_TOT;

  for (int base = blockIdx.x * RR; base < n; base += gridDim.x * RR) {
    int nb = n - base; if (nb > RR) nb = RR;
    __syncthreads();                 // protect LDS reuse across row groups
    if (tid < RR) ncand[tid] = 0;
    if (tid == 0) ovf = 0;
    if (tid < nb) {
      int m = flagged[base + tid];
      rowm[tid] = m;
      rzz[tid] = zzf[m];
      float v1 = flagv1[base + tid];
      float u = ldexpf(1.0f, ilogbf(v1) - 23);
      rthr[tid] = v1 + 4.0f * u + 2.5e-5f;
    }
    __syncthreads();
    {
      int r = tid >> 5;               // 8 rows x 32 threads
      int kk = (tid & 31) * 8;
      if (r < nb) {
        size_t m = (size_t)rowm[r];
        *reinterpret_cast<float4*>(&zs[r][kk]) =
            *reinterpret_cast<const float4*>(z + m * D_DIM + kk);
        *reinterpret_cast<float4*>(&zs[r][kk + 4]) =
            *reinterpret_cast<const float4*>(z + m * D_DIM + kk + 4);
      }
    }
    __syncthreads();

    // --- phase A: f32 scan, collect candidates ---
    for (int j = tid; j < NE; j += 256) {
      const float4* er = reinterpret_cast<const float4*>(emb + (size_t)j * D_DIM);
      float acc[RR];
#pragma unroll
      for (int r = 0; r < RR; ++r) acc[r] = 0.f;
      for (int k4 = 0; k4 < D_DIM / 4; ++k4) {
        float4 ev = er[k4];
#pragma unroll
        for (int r = 0; r < RR; ++r) {
          float4 zv = *reinterpret_cast<const float4*>(&zs[r][k4 * 4]);
          float a = acc[r];
          a = fmaf(zv.x, ev.x, a);
          a = fmaf(zv.y, ev.y, a);
          a = fmaf(zv.z, ev.z, a);
          a = fmaf(zv.w, ev.w, a);
          acc[r] = a;
        }
      }
      float ef = enf[j];
#pragma unroll
      for (int r = 0; r < RR; ++r) {
        float t = rzz[r] - 2.0f * acc[r];
        float dv = t + ef;
        if (r < nb && dv <= rthr[r]) {
          int p = atomicAdd(&ncand[r], 1);
          if (p < CAND_CAP) cj[r][p] = j;
          else atomicOr(&ovf, 1 << r);
        }
      }
    }
    __syncthreads();

    // --- phase B: exact f64 eval of candidates (1 thread per candidate) ---
    {
      int r = tid >> 5, c = tid & 31;
      if (r < nb && !((ovf >> r) & 1)) {
        int nc = ncand[r]; if (nc > CAND_CAP) nc = CAND_CAP;
        if (c < nc) {
          int j = cj[r][c];
          const float4* er = reinterpret_cast<const float4*>(emb + (size_t)j * D_DIM);
          double a = 0.0;
#pragma unroll 4
          for (int k4 = 0; k4 < D_DIM / 4; ++k4) {
            float4 ev = er[k4];
            float4 zv = *reinterpret_cast<const float4*>(&zs[r][k4 * 4]);
            a = fma((double)zv.x, (double)ev.x, a);
            a = fma((double)zv.y, (double)ev.y, a);
            a = fma((double)zv.z, (double)ev.z, a);
            a = fma((double)zv.w, (double)ev.w, a);
          }
          float zef = (float)a;                 // correctly-rounded f32(ze)
          float t = rzz[r] - 2.0f * zef;
          cdv[r][c] = t + enf[j];
        }
      }
    }
    __syncthreads();
    if (tid < nb && !((ovf >> tid) & 1)) {
      int nc = ncand[tid]; if (nc > CAND_CAP) nc = CAND_CAP;
      float bvv = INFINITY; int bjj = 0x7FFFFFFF;
      for (int c = 0; c < nc; ++c) {
        float dv = cdv[tid][c]; int j = cj[tid][c];
        if (dv < bvv || (dv == bvv && j < bjj)) { bvv = dv; bjj = j; }
      }
      idx_ws[rowm[tid]] = bjj;
    }
    __syncthreads();

    // --- overflow fallback: full f64 scan (ovf is LDS-uniform) ---
    for (int r = 0; r < nb; ++r) {
      if (!((ovf >> r) & 1)) continue;
      float bvv = INFINITY; int bjj = 0;
      for (int j = tid; j < NE; j += 256) {
        const float4* er = reinterpret_cast<const float4*>(emb + (size_t)j * D_DIM);
        double a = 0.0;
        for (int k4 = 0; k4 < D_DIM / 4; ++k4) {
          float4 ev = er[k4];
          float4 zv = *reinterpret_cast<const float4*>(&zs[r][k4 * 4]);
          a = fma((double)zv.x, (double)ev.x, a);
          a = fma((double)zv.y, (double)ev.y, a);
          a = fma((double)zv.z, (double)ev.z, a);
          a = fma((double)zv.w, (double)ev.w, a);
        }
        float zef = (float)a;
        float t = rzz[r] - 2.0f * zef;
        float dv = t + enf[j];
        if (dv < bvv) { bvv = dv; bjj = j; }
      }
      rv[tid] = bvv; rj[tid] = bjj;
      __syncthreads();
      for (int s = 128; s > 0; s >>= 1) {
        if (tid < s) {
          float ov = rv[tid + s]; int oj = rj[tid + s];
          if (ov < rv[tid] || (ov == rv[tid] && oj < rj[tid])) {
            rv[tid] = ov; rj[tid] = oj;
          }
        }
        __syncthreads();
      }
      if (tid == 0) idx_ws[rowm[r]] = rj[0];
      __syncthreads();
    }
  }
}

// ---------------------------------------------------------------------------
// Kernel 5: idx (as float), age reset, usage histogram — after refine.
__global__ __launch_bounds__(256) void vq_scatter(
    const int* __restrict__ idx_ws, float* __restrict__ out) {
  int m = blockIdx.x * 256 + threadIdx.x;
  if (m >= M_TOT) return;
  int j = idx_ws[m];
  out[O_IDX + m] = (float)j;
  out[O_AGE + j] = 0.0f;            // benign race: all write 0
  atomicAdd(&out[O_USAGE + j], 1.0f);
}

// ---------------------------------------------------------------------------
// Kernel 6: z_q_st = z + (q - z) (mimics ref rounding), loss accumulation
// (one atomic per block via LDS wave-partials).
__global__ __launch_bounds__(256) void vq_gather(
    const float* __restrict__ z, const float* __restrict__ emb,
    const int* __restrict__ idx_ws, float* __restrict__ out) {
  __shared__ float lsum[4];
  size_t e4 = (size_t)blockIdx.x * 256 + threadIdx.x;  // float4 index
  size_t m = e4 >> 6;       // / (D/4)
  int dq = (int)(e4 & 63);
  int j = idx_ws[m];
  float4 q = *reinterpret_cast<const float4*>(emb + (size_t)j * D_DIM + dq * 4);
  float4 zv = *reinterpret_cast<const float4*>(z + e4 * 4);
  float dx = q.x - zv.x, dy = q.y - zv.y, dz = q.z - zv.z, dw = q.w - zv.w;
  float4 o;
  o.x = zv.x + dx; o.y = zv.y + dy; o.z = zv.z + dz; o.w = zv.w + dw;
  *reinterpret_cast<float4*>(out + e4 * 4) = o;
  float ls = dx * dx + dy * dy + dz * dz + dw * dw;
#pragma unroll
  for (int off = 32; off > 0; off >>= 1) ls += __shfl_down(ls, off, 64);
  if ((threadIdx.x & 63) == 0) lsum[threadIdx.x >> 6] = ls;
  __syncthreads();
  if (threadIdx.x == 0)
    atomicAdd(out + O_LOSS,
              (lsum[0] + lsum[1] + lsum[2] + lsum[3]) * (1.25f / 8388608.f));
}

// ---------------------------------------------------------------------------
// ws layout (f32 slots): zzf[32768] | enf[8192] | idx_ws[32768] | cnt |
//   flagged[32768] | flagv1[32768] | pv1[2*32768] | pv2[2*32768] |
//   pj1[2*32768] | emb_h[1048576] | emb_l[1048576]   (~9.3 MB)
extern "C" void kernel_launch(void* const* d_in, const int* in_sizes, int n_in,
                              void* d_out, int out_size, void* d_ws, size_t ws_size,
                              hipStream_t stream) {
  const float* z = (const float*)d_in[0];
  const float* emb = (const float*)d_in[1];
  const float* code_age = (const float*)d_in[2];
  const float* code_usage = (const float*)d_in[3];
  float* out = (float*)d_out;

  float* zzf = (float*)d_ws;
  float* enf = zzf + M_TOT;
  int* idx_ws = (int*)(enf + NE);
  int* cnt = idx_ws + M_TOT;
  int* flagged = cnt + 1;
  float* flagv1 = (float*)(flagged + M_TOT);
  float* pv1 = flagv1 + M_TOT;
  float* pv2 = pv1 + MSPLIT * M_TOT;
  int* pj1 = (int*)(pv2 + MSPLIT * M_TOT);
  short* emb_h = (short*)(pj1 + MSPLIT * M_TOT);
  short* emb_l = emb_h + (size_t)NE * D_DIM;

  const size_t ws_need = (size_t)((char*)(emb_l + (size_t)NE * D_DIM) - (char*)d_ws);
  const bool presplit = ws_size >= ws_need;   // ws_size is constant -> deterministic

  hipLaunchKernelGGL(vq_prep, dim3(M_TOT / 256), dim3(256), 0, stream,
                     z, emb, code_age, code_usage, out, zzf, enf, cnt);
  if (presplit) {
    hipLaunchKernelGGL(vq_split, dim3(NE * (D_DIM / 4) / 256), dim3(256), 0, stream,
                       emb, emb_h, emb_l);
    hipLaunchKernelGGL((vq_argmin_mfma<1>), dim3(M_TOT / 128), dim3(512), 0, stream,
                       z, emb, emb_h, emb_l, zzf, enf, pv1, pv2, pj1);
  } else {
    hipLaunchKernelGGL((vq_argmin_mfma<0>), dim3(M_TOT / 128), dim3(512), 0, stream,
                       z, emb, emb_h, emb_l, zzf, enf, pv1, pv2, pj1);
  }
  hipLaunchKernelGGL(vq_merge, dim3(M_TOT / 256), dim3(256), 0, stream,
                     pv1, pv2, pj1, idx_ws, cnt, flagged, flagv1);
  hipLaunchKernelGGL(vq_refine, dim3(512), dim3(256), 0, stream,
                     z, emb, zzf, enf, idx_ws, cnt, flagged, flagv1);
  hipLaunchKernelGGL(vq_scatter, dim3(M_TOT / 256), dim3(256), 0, stream,
                     idx_ws, out);
  hipLaunchKernelGGL(vq_gather, dim3((M_TOT * (D_DIM / 4)) / 256), dim3(256), 0, stream,
                     z, emb, idx_ws, out);
}

// Round 10
// 1062.471 us; speedup vs baseline: 1.3989x; 1.2746x over previous
//
#include <hip/hip_runtime.h>
#include <math.h>

// Problem constants (z: [2,16384,256] f32, emb: [8192,256] f32)
#define D_DIM 256
#define NE    8192
#define M_TOT 32768L

// Output layout (f32 elements): z_q_st | loss | idx | age | usage
#define O_LOSS  8388608L
#define O_IDX   8388609L
#define O_AGE   8421377L
#define O_USAGE 8429569L

typedef __attribute__((ext_vector_type(8))) short bf16x8;
typedef __attribute__((ext_vector_type(4))) short bf16x4;
typedef __attribute__((ext_vector_type(4))) float f32x4;

__device__ __forceinline__ short f2bf(float f) {   // RNE f32 -> bf16 bits
  unsigned u = __float_as_uint(f);
  u += 0x7FFFu + ((u >> 16) & 1u);
  return (short)(u >> 16);
}
__device__ __forceinline__ float bf2f(short s) {
  return __uint_as_float(((unsigned)(unsigned short)s) << 16);
}

// ---------------------------------------------------------------------------
// Kernel 1: f32 row norms (f64-accumulated, f32-rounded) for z and emb,
// init age/usage defaults, zero loss + flag counter.
__global__ __launch_bounds__(256) void vq_prep(
    const float* __restrict__ z, const float* __restrict__ emb,
    const float* __restrict__ code_age, const float* __restrict__ code_usage,
    float* __restrict__ out, float* __restrict__ zzf, float* __restrict__ enf,
    int* __restrict__ cnt) {
  int t = blockIdx.x * 256 + threadIdx.x;  // 0..32767
  {
    const float4* row = reinterpret_cast<const float4*>(z + (size_t)t * D_DIM);
    double s = 0.0;
#pragma unroll
    for (int q = 0; q < D_DIM / 4; ++q) {
      float4 v = row[q];
      s = fma((double)v.x, (double)v.x, s);
      s = fma((double)v.y, (double)v.y, s);
      s = fma((double)v.z, (double)v.z, s);
      s = fma((double)v.w, (double)v.w, s);
    }
    zzf[t] = (float)s;
  }
  if (t < NE) {
    const float4* row = reinterpret_cast<const float4*>(emb + (size_t)t * D_DIM);
    double s = 0.0;
#pragma unroll
    for (int q = 0; q < D_DIM / 4; ++q) {
      float4 v = row[q];
      s = fma((double)v.x, (double)v.x, s);
      s = fma((double)v.y, (double)v.y, s);
      s = fma((double)v.z, (double)v.z, s);
      s = fma((double)v.w, (double)v.w, s);
    }
    enf[t] = (float)s;
    out[O_AGE + t] = code_age[t] + 1.0f;
    out[O_USAGE + t] = code_usage[t];
    if (t == 0) { out[O_LOSS] = 0.0f; *cnt = 0; }
  }
}

// ---------------------------------------------------------------------------
// Kernel 1b: split emb into bf16 hi/lo planes (row-major) once.
__global__ __launch_bounds__(256) void vq_split(
    const float* __restrict__ emb, short* __restrict__ emb_h,
    short* __restrict__ emb_l) {
  int e4 = blockIdx.x * 256 + threadIdx.x;      // float4 index over 8192*64
  float4 v = reinterpret_cast<const float4*>(emb)[e4];
  float s[4] = {v.x, v.y, v.z, v.w};
  short h[4], l[4];
#pragma unroll
  for (int i = 0; i < 4; ++i) {
    h[i] = f2bf(s[i]);
    l[i] = f2bf(s[i] - bf2f(h[i]));
  }
  *reinterpret_cast<bf16x4*>(emb_h + (size_t)e4 * 4) = (bf16x4){h[0], h[1], h[2], h[3]};
  *reinterpret_cast<bf16x4*>(emb_l + (size_t)e4 * 4) = (bf16x4){l[0], l[1], l[2], l[3]};
}

// ---------------------------------------------------------------------------
// Kernel 2: split-bf16 MFMA argmin pass, double-buffered LDS + raw-barrier
// pipeline (one barrier per ks, vmcnt NOT drained at barriers).
// 256 blocks x 512 threads (8 waves: 4 row-groups x 2 col-groups).
// Block tile 128 rows x full 8192 codes. Wave tile 32x64.
// ze = zl*eh + zh*eh + zh*el (3 MFMA, f32 acc).
// Epilogue: dv = fl(fl(zz-2*ze)+en), per-row top-2, lowest-index ties.
#define LDK 40   // shorts per LDS row (32 + 8 pad) -> 80 B stride, 2-way banks
#define LSLICE (128 * LDK)

template <int PRESPLIT>
__global__ __launch_bounds__(512, 2) void vq_argmin_mfma(
    const float* __restrict__ z, const float* __restrict__ emb,
    const short* __restrict__ emb_h, const short* __restrict__ emb_l,
    const float* __restrict__ zzf, const float* __restrict__ enf,
    float* __restrict__ pv1, float* __restrict__ pv2, int* __restrict__ pj1) {
  __shared__ short th[2][LSLICE];
  __shared__ short tl[2][LSLICE];

  const int tid = threadIdx.x;
  const int lane = tid & 63;
  const int wave = tid >> 6;        // 0..7
  const int wr = wave >> 1;         // row group 0..3
  const int wc = wave & 1;          // col group 0..1
  const int lrow = lane & 15;
  const int lq = lane >> 4;         // 0..3
  const size_t row0 = (size_t)blockIdx.x * 128;

  const int srow = tid >> 2;        // staging: 0..127
  const int skq = (tid & 3) * 8;    // staging k offset (elements): 0,8,16,24

  // ---- phase 1: split A (z rows) into register fragments, full K ----
  bf16x8 afh[2][8], afl[2][8];
#pragma unroll
  for (int ks = 0; ks < 8; ++ks) {
    __syncthreads();
    {
      const float* src = z + (row0 + srow) * (size_t)D_DIM + ks * 32 + skq;
      float4 v0 = *reinterpret_cast<const float4*>(src);
      float4 v1 = *reinterpret_cast<const float4*>(src + 4);
      float s[8] = {v0.x, v0.y, v0.z, v0.w, v1.x, v1.y, v1.z, v1.w};
      short h[8], l[8];
#pragma unroll
      for (int i = 0; i < 8; ++i) {
        h[i] = f2bf(s[i]);
        l[i] = f2bf(s[i] - bf2f(h[i]));
      }
      *reinterpret_cast<bf16x4*>(&th[0][srow * LDK + skq]) = (bf16x4){h[0], h[1], h[2], h[3]};
      *reinterpret_cast<bf16x4*>(&th[0][srow * LDK + skq + 4]) = (bf16x4){h[4], h[5], h[6], h[7]};
      *reinterpret_cast<bf16x4*>(&tl[0][srow * LDK + skq]) = (bf16x4){l[0], l[1], l[2], l[3]};
      *reinterpret_cast<bf16x4*>(&tl[0][srow * LDK + skq + 4]) = (bf16x4){l[4], l[5], l[6], l[7]};
    }
    __syncthreads();
#pragma unroll
    for (int rt = 0; rt < 2; ++rt) {
      int r = wr * 32 + rt * 16 + lrow;
      afh[rt][ks] = *reinterpret_cast<const bf16x8*>(&th[0][r * LDK + lq * 8]);
      afl[rt][ks] = *reinterpret_cast<const bf16x8*>(&tl[0][r * LDK + lq * 8]);
    }
  }

  // per-lane row slots: slot s=rt*4+rr -> row row0 + wr*32 + rt*16 + lq*4 + rr
  float zrow2[8];
#pragma unroll
  for (int rt = 0; rt < 2; ++rt)
#pragma unroll
    for (int rr = 0; rr < 4; ++rr)
      zrow2[rt * 4 + rr] = zzf[row0 + wr * 32 + rt * 16 + lq * 4 + rr];

  float bv1[8], bv2[8];
  int bj1[8];
#pragma unroll
  for (int s = 0; s < 8; ++s) { bv1[s] = INFINITY; bv2[s] = INFINITY; bj1[s] = 0; }

  // staging registers: slice s+1 data (PRESPLIT: pre-split planes; else f32)
  bf16x8 ph, pl;
  float4 pf0, pf1;

  // ---- prologue: slice 0 -> buf[0]; slice 1 -> regs (in flight) ----
  if (PRESPLIT) {
    ph = *reinterpret_cast<const bf16x8*>(emb_h + (size_t)srow * D_DIM + skq);
    pl = *reinterpret_cast<const bf16x8*>(emb_l + (size_t)srow * D_DIM + skq);
  } else {
    const float* src = emb + (size_t)srow * D_DIM + skq;
    pf0 = *reinterpret_cast<const float4*>(src);
    pf1 = *reinterpret_cast<const float4*>(src + 4);
  }
  __syncthreads();   // phase-1 reads of th[0]/tl[0] complete (full drain, once)
  if (PRESPLIT) {
    *reinterpret_cast<bf16x8*>(&th[0][srow * LDK + skq]) = ph;
    *reinterpret_cast<bf16x8*>(&tl[0][srow * LDK + skq]) = pl;
    ph = *reinterpret_cast<const bf16x8*>(emb_h + (size_t)srow * D_DIM + 32 + skq);
    pl = *reinterpret_cast<const bf16x8*>(emb_l + (size_t)srow * D_DIM + 32 + skq);
  } else {
    float s[8] = {pf0.x, pf0.y, pf0.z, pf0.w, pf1.x, pf1.y, pf1.z, pf1.w};
    short h[8], l[8];
#pragma unroll
    for (int i = 0; i < 8; ++i) {
      h[i] = f2bf(s[i]);
      l[i] = f2bf(s[i] - bf2f(h[i]));
    }
    *reinterpret_cast<bf16x4*>(&th[0][srow * LDK + skq]) = (bf16x4){h[0], h[1], h[2], h[3]};
    *reinterpret_cast<bf16x4*>(&th[0][srow * LDK + skq + 4]) = (bf16x4){h[4], h[5], h[6], h[7]};
    *reinterpret_cast<bf16x4*>(&tl[0][srow * LDK + skq]) = (bf16x4){l[0], l[1], l[2], l[3]};
    *reinterpret_cast<bf16x4*>(&tl[0][srow * LDK + skq + 4]) = (bf16x4){l[4], l[5], l[6], l[7]};
    const float* src = emb + (size_t)srow * D_DIM + 32 + skq;
    pf0 = *reinterpret_cast<const float4*>(src);
    pf1 = *reinterpret_cast<const float4*>(src + 4);
  }
  asm volatile("s_waitcnt lgkmcnt(0)" ::: "memory");
  __builtin_amdgcn_s_barrier();
  asm volatile("" ::: "memory");

  // ---- main loop: invariant at (jt,ks): buf[ks&1] holds slice s=jt*8+ks,
  // regs hold slice s+1 (loads possibly in flight, counted vmcnt covers) ----
  for (int jt0 = 0; jt0 < NE; jt0 += 128) {
    float enq[4];
#pragma unroll
    for (int ct = 0; ct < 4; ++ct) enq[ct] = enf[jt0 + wc * 64 + ct * 16 + lrow];

    f32x4 acc[2][4];
#pragma unroll
    for (int rt = 0; rt < 2; ++rt)
#pragma unroll
      for (int ct = 0; ct < 4; ++ct) acc[rt][ct] = (f32x4){0.f, 0.f, 0.f, 0.f};

#pragma unroll
    for (int ks = 0; ks < 8; ++ks) {
      const int p = ks & 1;
      // hi-plane B fragments + 16 MFMA
      bf16x8 bfh[4];
#pragma unroll
      for (int ct = 0; ct < 4; ++ct) {
        int c = wc * 64 + ct * 16 + lrow;
        bfh[ct] = *reinterpret_cast<const bf16x8*>(&th[p][c * LDK + lq * 8]);
      }
      __builtin_amdgcn_s_setprio(1);
#pragma unroll
      for (int rt = 0; rt < 2; ++rt)
#pragma unroll
        for (int ct = 0; ct < 4; ++ct) {
          acc[rt][ct] = __builtin_amdgcn_mfma_f32_16x16x32_bf16(
              afl[rt][ks], bfh[ct], acc[rt][ct], 0, 0, 0);   // zl*eh
          acc[rt][ct] = __builtin_amdgcn_mfma_f32_16x16x32_bf16(
              afh[rt][ks], bfh[ct], acc[rt][ct], 0, 0, 0);   // zh*eh
        }
      __builtin_amdgcn_s_setprio(0);

      // stage slice s+1 (regs) into buf[p^1]; compiler inserts counted vmcnt
      if (PRESPLIT) {
        *reinterpret_cast<bf16x8*>(&th[p ^ 1][srow * LDK + skq]) = ph;
        *reinterpret_cast<bf16x8*>(&tl[p ^ 1][srow * LDK + skq]) = pl;
      } else {
        float s[8] = {pf0.x, pf0.y, pf0.z, pf0.w, pf1.x, pf1.y, pf1.z, pf1.w};
        short h[8], l[8];
#pragma unroll
        for (int i = 0; i < 8; ++i) {
          h[i] = f2bf(s[i]);
          l[i] = f2bf(s[i] - bf2f(h[i]));
        }
        *reinterpret_cast<bf16x4*>(&th[p ^ 1][srow * LDK + skq]) = (bf16x4){h[0], h[1], h[2], h[3]};
        *reinterpret_cast<bf16x4*>(&th[p ^ 1][srow * LDK + skq + 4]) = (bf16x4){h[4], h[5], h[6], h[7]};
        *reinterpret_cast<bf16x4*>(&tl[p ^ 1][srow * LDK + skq]) = (bf16x4){l[0], l[1], l[2], l[3]};
        *reinterpret_cast<bf16x4*>(&tl[p ^ 1][srow * LDK + skq + 4]) = (bf16x4){l[4], l[5], l[6], l[7]};
      }
      // issue prefetch of slice s+2 (stays in flight across the raw barrier)
      {
        int s2 = jt0 / 16 + ks + 2;            // jt0/16 == jt*8
        if (s2 > 511) s2 = 511;
        const size_t off = ((size_t)((s2 >> 3) * 128 + srow)) * D_DIM + (s2 & 7) * 32 + skq;
        if (PRESPLIT) {
          ph = *reinterpret_cast<const bf16x8*>(emb_h + off);
          pl = *reinterpret_cast<const bf16x8*>(emb_l + off);
        } else {
          pf0 = *reinterpret_cast<const float4*>(emb + off);
          pf1 = *reinterpret_cast<const float4*>(emb + off + 4);
        }
      }

      // lo-plane B fragments + 8 MFMA
      bf16x8 bfl[4];
#pragma unroll
      for (int ct = 0; ct < 4; ++ct) {
        int c = wc * 64 + ct * 16 + lrow;
        bfl[ct] = *reinterpret_cast<const bf16x8*>(&tl[p][c * LDK + lq * 8]);
      }
      __builtin_amdgcn_s_setprio(1);
#pragma unroll
      for (int rt = 0; rt < 2; ++rt)
#pragma unroll
        for (int ct = 0; ct < 4; ++ct)
          acc[rt][ct] = __builtin_amdgcn_mfma_f32_16x16x32_bf16(
              afh[rt][ks], bfl[ct], acc[rt][ct], 0, 0, 0);   // zh*el
      __builtin_amdgcn_s_setprio(0);

      // raw barrier: own LDS ops drained (lgkm), vmcnt NOT drained
      asm volatile("s_waitcnt lgkmcnt(0)" ::: "memory");
      __builtin_amdgcn_s_barrier();
      asm volatile("" ::: "memory");
    }

    // epilogue: reference f32 chain; ct ascending + jt ascending + strict <
    // -> lowest index on ties
#pragma unroll
    for (int ct = 0; ct < 4; ++ct) {
      int gj = jt0 + wc * 64 + ct * 16 + lrow;
      float ef = enq[ct];
#pragma unroll
      for (int rt = 0; rt < 2; ++rt)
#pragma unroll
        for (int rr = 0; rr < 4; ++rr) {
          int s = rt * 4 + rr;
          float t = zrow2[s] - 2.0f * acc[rt][ct][rr];
          float dv = t + ef;
          bj1[s] = (dv < bv1[s]) ? gj : bj1[s];
          bv2[s] = fminf(bv2[s], fmaxf(dv, bv1[s]));
          bv1[s] = fminf(bv1[s], dv);
        }
    }
  }

  // reduce top-2 across the 16 code-lanes (lrow) of each lane quarter
#pragma unroll
  for (int m = 1; m < 16; m <<= 1) {
#pragma unroll
    for (int s = 0; s < 8; ++s) {
      float ov1 = __shfl_xor(bv1[s], m, 16);
      float ov2 = __shfl_xor(bv2[s], m, 16);
      int oj1 = __shfl_xor(bj1[s], m, 16);
      if (ov1 < bv1[s] || (ov1 == bv1[s] && oj1 < bj1[s])) {
        bv2[s] = fminf(bv1[s], ov2);
        bv1[s] = ov1; bj1[s] = oj1;
      } else {
        bv2[s] = fminf(bv2[s], ov1);
      }
    }
  }
  if (lrow == 0) {
#pragma unroll
    for (int s = 0; s < 8; ++s) {
      size_t grow = row0 + wr * 32 + (s >> 2) * 16 + lq * 4 + (s & 3);
      size_t o = (size_t)wc * M_TOT + grow;
      pv1[o] = bv1[s]; pv2[o] = bv2[s]; pj1[o] = bj1[s];
    }
  }
}

// ---------------------------------------------------------------------------
// Kernel 3: fold the 2 col-split partial top-2s per row; flag ambiguous rows
// (also exporting v1 so refine can bound its candidate search).
#define MSPLIT 2

__global__ __launch_bounds__(256) void vq_merge(
    const float* __restrict__ pv1, const float* __restrict__ pv2,
    const int* __restrict__ pj1, int* __restrict__ idx_ws,
    int* __restrict__ cnt, int* __restrict__ flagged,
    float* __restrict__ flagv1) {
  int m = blockIdx.x * 256 + threadIdx.x;
  if (m >= M_TOT) return;
  float v1 = INFINITY, v2 = INFINITY;
  int j1 = 0;
#pragma unroll
  for (int s = 0; s < MSPLIT; ++s) {
    float a1 = pv1[(size_t)s * M_TOT + m];
    float a2 = pv2[(size_t)s * M_TOT + m];
    int aj = pj1[(size_t)s * M_TOT + m];
    if (a1 < v1 || (a1 == v1 && aj < j1)) {
      v2 = fminf(v1, a2); v1 = a1; j1 = aj;
    } else {
      v2 = fminf(v2, a1);
    }
  }
  idx_ws[m] = j1;
  float u = ldexpf(1.0f, ilogbf(v2) - 23);
  if (v2 - v1 <= 2.0f * u + 1e-5f) {
    int p = atomicAdd(cnt, 1);
    flagged[p] = m;
    flagv1[p] = v1;
  }
}

// ---------------------------------------------------------------------------
// Kernel 4: refine flagged rows, two-phase.
//  A) f32-dot scan of all 8192 codes; every j with dv <= v1 + CMARG is a
//     candidate (provably includes the ref argmin).
//  B) exact f64 dot per candidate -> ref f32 chain -> min, lowest-index ties.
//     Deterministic overflow fallback: full f64 scan if cap exceeded.
#define RR 8
#define CAND_CAP 32

__global__ __launch_bounds__(256) void vq_refine(
    const float* __restrict__ z, const float* __restrict__ emb,
    const float* __restrict__ zzf, const float* __restrict__ enf,
    int* __restrict__ idx_ws, const int* __restrict__ cnt,
    const int* __restrict__ flagged, const float* __restrict__ flagv1) {
  __shared__ float zs[RR][D_DIM];
  __shared__ float rzz[RR];
  __shared__ float rthr[RR];
  __shared__ int rowm[RR];
  __shared__ int ncand[RR];
  __shared__ int cj[RR][CAND_CAP];
  __shared__ float cdv[RR][CAND_CAP];
  __shared__ float rv[256];
  __shared__ int rj[256];
  __shared__ int ovf;

  const int tid = threadIdx.x;
  int n = *cnt;
  if (n > (int)M_TOT) n = (int)M_TOT;

  for (int base = blockIdx.x * RR; base < n; base += gridDim.x * RR) {
    int nb = n - base; if (nb > RR) nb = RR;
    __syncthreads();                 // protect LDS reuse across row groups
    if (tid < RR) ncand[tid] = 0;
    if (tid == 0) ovf = 0;
    if (tid < nb) {
      int m = flagged[base + tid];
      rowm[tid] = m;
      rzz[tid] = zzf[m];
      float v1 = flagv1[base + tid];
      float u = ldexpf(1.0f, ilogbf(v1) - 23);
      rthr[tid] = v1 + 4.0f * u + 2.5e-5f;
    }
    __syncthreads();
    {
      int r = tid >> 5;               // 8 rows x 32 threads
      int kk = (tid & 31) * 8;
      if (r < nb) {
        size_t m = (size_t)rowm[r];
        *reinterpret_cast<float4*>(&zs[r][kk]) =
            *reinterpret_cast<const float4*>(z + m * D_DIM + kk);
        *reinterpret_cast<float4*>(&zs[r][kk + 4]) =
            *reinterpret_cast<const float4*>(z + m * D_DIM + kk + 4);
      }
    }
    __syncthreads();

    // --- phase A: f32 scan, collect candidates ---
    for (int j = tid; j < NE; j += 256) {
      const float4* er = reinterpret_cast<const float4*>(emb + (size_t)j * D_DIM);
      float acc[RR];
#pragma unroll
      for (int r = 0; r < RR; ++r) acc[r] = 0.f;
      for (int k4 = 0; k4 < D_DIM / 4; ++k4) {
        float4 ev = er[k4];
#pragma unroll
        for (int r = 0; r < RR; ++r) {
          float4 zv = *reinterpret_cast<const float4*>(&zs[r][k4 * 4]);
          float a = acc[r];
          a = fmaf(zv.x, ev.x, a);
          a = fmaf(zv.y, ev.y, a);
          a = fmaf(zv.z, ev.z, a);
          a = fmaf(zv.w, ev.w, a);
          acc[r] = a;
        }
      }
      float ef = enf[j];
#pragma unroll
      for (int r = 0; r < RR; ++r) {
        float t = rzz[r] - 2.0f * acc[r];
        float dv = t + ef;
        if (r < nb && dv <= rthr[r]) {
          int p = atomicAdd(&ncand[r], 1);
          if (p < CAND_CAP) cj[r][p] = j;
          else atomicOr(&ovf, 1 << r);
        }
      }
    }
    __syncthreads();

    // --- phase B: exact f64 eval of candidates (1 thread per candidate) ---
    {
      int r = tid >> 5, c = tid & 31;
      if (r < nb && !((ovf >> r) & 1)) {
        int nc = ncand[r]; if (nc > CAND_CAP) nc = CAND_CAP;
        if (c < nc) {
          int j = cj[r][c];
          const float4* er = reinterpret_cast<const float4*>(emb + (size_t)j * D_DIM);
          double a = 0.0;
#pragma unroll 4
          for (int k4 = 0; k4 < D_DIM / 4; ++k4) {
            float4 ev = er[k4];
            float4 zv = *reinterpret_cast<const float4*>(&zs[r][k4 * 4]);
            a = fma((double)zv.x, (double)ev.x, a);
            a = fma((double)zv.y, (double)ev.y, a);
            a = fma((double)zv.z, (double)ev.z, a);
            a = fma((double)zv.w, (double)ev.w, a);
          }
          float zef = (float)a;                 // correctly-rounded f32(ze)
          float t = rzz[r] - 2.0f * zef;
          cdv[r][c] = t + enf[j];
        }
      }
    }
    __syncthreads();
    if (tid < nb && !((ovf >> tid) & 1)) {
      int nc = ncand[tid]; if (nc > CAND_CAP) nc = CAND_CAP;
      float bvv = INFINITY; int bjj = 0x7FFFFFFF;
      for (int c = 0; c < nc; ++c) {
        float dv = cdv[tid][c]; int j = cj[tid][c];
        if (dv < bvv || (dv == bvv && j < bjj)) { bvv = dv; bjj = j; }
      }
      idx_ws[rowm[tid]] = bjj;
    }
    __syncthreads();

    // --- overflow fallback: full f64 scan (ovf is LDS-uniform) ---
    for (int r = 0; r < nb; ++r) {
      if (!((ovf >> r) & 1)) continue;
      float bvv = INFINITY; int bjj = 0;
      for (int j = tid; j < NE; j += 256) {
        const float4* er = reinterpret_cast<const float4*>(emb + (size_t)j * D_DIM);
        double a = 0.0;
        for (int k4 = 0; k4 < D_DIM / 4; ++k4) {
          float4 ev = er[k4];
          float4 zv = *reinterpret_cast<const float4*>(&zs[r][k4 * 4]);
          a = fma((double)zv.x, (double)ev.x, a);
          a = fma((double)zv.y, (double)ev.y, a);
          a = fma((double)zv.z, (double)ev.z, a);
          a = fma((double)zv.w, (double)ev.w, a);
        }
        float zef = (float)a;
        float t = rzz[r] - 2.0f * zef;
        float dv = t + enf[j];
        if (dv < bvv) { bvv = dv; bjj = j; }
      }
      rv[tid] = bvv; rj[tid] = bjj;
      __syncthreads();
      for (int s = 128; s > 0; s >>= 1) {
        if (tid < s) {
          float ov = rv[tid + s]; int oj = rj[tid + s];
          if (ov < rv[tid] || (ov == rv[tid] && oj < rj[tid])) {
            rv[tid] = ov; rj[tid] = oj;
          }
        }
        __syncthreads();
      }
      if (tid == 0) idx_ws[rowm[r]] = rj[0];
      __syncthreads();
    }
  }
}

// ---------------------------------------------------------------------------
// Kernel 5: idx (as float), age reset, usage histogram — after refine.
__global__ __launch_bounds__(256) void vq_scatter(
    const int* __restrict__ idx_ws, float* __restrict__ out) {
  int m = blockIdx.x * 256 + threadIdx.x;
  if (m >= M_TOT) return;
  int j = idx_ws[m];
  out[O_IDX + m] = (float)j;
  out[O_AGE + j] = 0.0f;            // benign race: all write 0
  atomicAdd(&out[O_USAGE + j], 1.0f);
}

// ---------------------------------------------------------------------------
// Kernel 6: z_q_st = z + (q - z) (mimics ref rounding), loss accumulation
// (one atomic per block via LDS wave-partials).
__global__ __launch_bounds__(256) void vq_gather(
    const float* __restrict__ z, const float* __restrict__ emb,
    const int* __restrict__ idx_ws, float* __restrict__ out) {
  __shared__ float lsum[4];
  size_t e4 = (size_t)blockIdx.x * 256 + threadIdx.x;  // float4 index
  size_t m = e4 >> 6;       // / (D/4)
  int dq = (int)(e4 & 63);
  int j = idx_ws[m];
  float4 q = *reinterpret_cast<const float4*>(emb + (size_t)j * D_DIM + dq * 4);
  float4 zv = *reinterpret_cast<const float4*>(z + e4 * 4);
  float dx = q.x - zv.x, dy = q.y - zv.y, dz = q.z - zv.z, dw = q.w - zv.w;
  float4 o;
  o.x = zv.x + dx; o.y = zv.y + dy; o.z = zv.z + dz; o.w = zv.w + dw;
  *reinterpret_cast<float4*>(out + e4 * 4) = o;
  float ls = dx * dx + dy * dy + dz * dz + dw * dw;
#pragma unroll
  for (int off = 32; off > 0; off >>= 1) ls += __shfl_down(ls, off, 64);
  if ((threadIdx.x & 63) == 0) lsum[threadIdx.x >> 6] = ls;
  __syncthreads();
  if (threadIdx.x == 0)
    atomicAdd(out + O_LOSS,
              (lsum[0] + lsum[1] + lsum[2] + lsum[3]) * (1.25f / 8388608.f));
}

// ---------------------------------------------------------------------------
// ws layout (f32 slots): zzf[32768] | enf[8192] | idx_ws[32768] | cnt |
//   flagged[32768] | flagv1[32768] | pv1[2*32768] | pv2[2*32768] |
//   pj1[2*32768] | emb_h[1048576 shorts] | emb_l[1048576 shorts]  (~9.3 MB)
extern "C" void kernel_launch(void* const* d_in, const int* in_sizes, int n_in,
                              void* d_out, int out_size, void* d_ws, size_t ws_size,
                              hipStream_t stream) {
  const float* z = (const float*)d_in[0];
  const float* emb = (const float*)d_in[1];
  const float* code_age = (const float*)d_in[2];
  const float* code_usage = (const float*)d_in[3];
  float* out = (float*)d_out;

  float* zzf = (float*)d_ws;
  float* enf = zzf + M_TOT;
  int* idx_ws = (int*)(enf + NE);
  int* cnt = idx_ws + M_TOT;
  int* flagged = cnt + 1;
  float* flagv1 = (float*)(flagged + M_TOT);
  float* pv1 = flagv1 + M_TOT;
  float* pv2 = pv1 + MSPLIT * M_TOT;
  int* pj1 = (int*)(pv2 + MSPLIT * M_TOT);
  short* emb_h = (short*)(pj1 + MSPLIT * M_TOT);
  short* emb_l = emb_h + (size_t)NE * D_DIM;

  const size_t ws_need = (size_t)((char*)(emb_l + (size_t)NE * D_DIM) - (char*)d_ws);
  const bool presplit = ws_size >= ws_need;   // ws_size constant -> deterministic

  hipLaunchKernelGGL(vq_prep, dim3(M_TOT / 256), dim3(256), 0, stream,
                     z, emb, code_age, code_usage, out, zzf, enf, cnt);
  if (presplit) {
    hipLaunchKernelGGL(vq_split, dim3(NE * (D_DIM / 4) / 256), dim3(256), 0, stream,
                       emb, emb_h, emb_l);
    hipLaunchKernelGGL((vq_argmin_mfma<1>), dim3(M_TOT / 128), dim3(512), 0, stream,
                       z, emb, emb_h, emb_l, zzf, enf, pv1, pv2, pj1);
  } else {
    hipLaunchKernelGGL((vq_argmin_mfma<0>), dim3(M_TOT / 128), dim3(512), 0, stream,
                       z, emb, emb_h, emb_l, zzf, enf, pv1, pv2, pj1);
  }
  hipLaunchKernelGGL(vq_merge, dim3(M_TOT / 256), dim3(256), 0, stream,
                     pv1, pv2, pj1, idx_ws, cnt, flagged, flagv1);
  hipLaunchKernelGGL(vq_refine, dim3(512), dim3(256), 0, stream,
                     z, emb, zzf, enf, idx_ws, cnt, flagged, flagv1);
  hipLaunchKernelGGL(vq_scatter, dim3(M_TOT / 256), dim3(256), 0, stream,
                     idx_ws, out);
  hipLaunchKernelGGL(vq_gather, dim3((M_TOT * (D_DIM / 4)) / 256), dim3(256), 0, stream,
                     z, emb, idx_ws, out);
}

// Round 11
// 637.014 us; speedup vs baseline: 2.3332x; 1.6679x over previous
//
#include <hip/hip_runtime.h>
#include <math.h>

// Problem constants (z: [2,16384,256] f32, emb: [8192,256] f32)
#define D_DIM 256
#define NE    8192
#define M_TOT 32768L

// Output layout (f32 elements): z_q_st | loss | idx | age | usage
#define O_LOSS  8388608L
#define O_IDX   8388609L
#define O_AGE   8421377L
#define O_USAGE 8429569L

typedef __attribute__((ext_vector_type(8))) short bf16x8;
typedef __attribute__((ext_vector_type(4))) short bf16x4;
typedef __attribute__((ext_vector_type(4))) float f32x4;

__device__ __forceinline__ short f2bf(float f) {   // RNE f32 -> bf16 bits
  unsigned u = __float_as_uint(f);
  u += 0x7FFFu + ((u >> 16) & 1u);
  return (short)(u >> 16);
}
__device__ __forceinline__ float bf2f(short s) {
  return __uint_as_float(((unsigned)(unsigned short)s) << 16);
}

// ---------------------------------------------------------------------------
// Kernel 1: f32 row norms (f64-accumulated, f32-rounded) for z and emb,
// init age/usage defaults, zero loss + flag counter.
__global__ __launch_bounds__(256) void vq_prep(
    const float* __restrict__ z, const float* __restrict__ emb,
    const float* __restrict__ code_age, const float* __restrict__ code_usage,
    float* __restrict__ out, float* __restrict__ zzf, float* __restrict__ enf,
    int* __restrict__ cnt) {
  int t = blockIdx.x * 256 + threadIdx.x;  // 0..32767
  {
    const float4* row = reinterpret_cast<const float4*>(z + (size_t)t * D_DIM);
    double s = 0.0;
#pragma unroll
    for (int q = 0; q < D_DIM / 4; ++q) {
      float4 v = row[q];
      s = fma((double)v.x, (double)v.x, s);
      s = fma((double)v.y, (double)v.y, s);
      s = fma((double)v.z, (double)v.z, s);
      s = fma((double)v.w, (double)v.w, s);
    }
    zzf[t] = (float)s;
  }
  if (t < NE) {
    const float4* row = reinterpret_cast<const float4*>(emb + (size_t)t * D_DIM);
    double s = 0.0;
#pragma unroll
    for (int q = 0; q < D_DIM / 4; ++q) {
      float4 v = row[q];
      s = fma((double)v.x, (double)v.x, s);
      s = fma((double)v.y, (double)v.y, s);
      s = fma((double)v.z, (double)v.z, s);
      s = fma((double)v.w, (double)v.w, s);
    }
    enf[t] = (float)s;
    out[O_AGE + t] = code_age[t] + 1.0f;
    out[O_USAGE + t] = code_usage[t];
    if (t == 0) { out[O_LOSS] = 0.0f; *cnt = 0; }
  }
}

// ---------------------------------------------------------------------------
// Kernel 1b: split emb into bf16 hi/lo planes (row-major) once.
__global__ __launch_bounds__(256) void vq_split(
    const float* __restrict__ emb, short* __restrict__ emb_h,
    short* __restrict__ emb_l) {
  int e4 = blockIdx.x * 256 + threadIdx.x;      // float4 index over 8192*64
  float4 v = reinterpret_cast<const float4*>(emb)[e4];
  float s[4] = {v.x, v.y, v.z, v.w};
  short h[4], l[4];
#pragma unroll
  for (int i = 0; i < 4; ++i) {
    h[i] = f2bf(s[i]);
    l[i] = f2bf(s[i] - bf2f(h[i]));
  }
  *reinterpret_cast<bf16x4*>(emb_h + (size_t)e4 * 4) = (bf16x4){h[0], h[1], h[2], h[3]};
  *reinterpret_cast<bf16x4*>(emb_l + (size_t)e4 * 4) = (bf16x4){l[0], l[1], l[2], l[3]};
}

// ---------------------------------------------------------------------------
// Kernel 2: split-bf16 MFMA argmin pass, double-buffered LDS + raw-barrier
// pipeline; code dim split x2 (grid (256,2) = 2 blocks/CU for latency hiding).
// 512 threads (8 waves: 4 row-groups x 2 col-groups). Block tile 128 rows x
// 4096 codes. ze = zl*eh + zh*eh + zh*el (3 MFMA, f32 acc).
// Epilogue: dv = fl(fl(zz-2*ze)+en), per-row top-2, lowest-index ties.
#define LDK 40   // shorts per LDS row (32 + 8 pad) -> 80 B stride, 2-way banks
#define LSLICE (128 * LDK)
#define CHUNK 4096           // codes per block in the main pass
#define MSPLIT 4             // partials per row = grid.y(2) x wc(2)

template <int PRESPLIT>
__global__ __launch_bounds__(512, 2) void vq_argmin_mfma(
    const float* __restrict__ z, const float* __restrict__ emb,
    const short* __restrict__ emb_h, const short* __restrict__ emb_l,
    const float* __restrict__ zzf, const float* __restrict__ enf,
    float* __restrict__ pv1, float* __restrict__ pv2, int* __restrict__ pj1) {
  __shared__ short th[2][LSLICE];
  __shared__ short tl[2][LSLICE];

  const int tid = threadIdx.x;
  const int lane = tid & 63;
  const int wave = tid >> 6;        // 0..7
  const int wr = wave >> 1;         // row group 0..3
  const int wc = wave & 1;          // col group 0..1
  const int lrow = lane & 15;
  const int lq = lane >> 4;         // 0..3
  const size_t row0 = (size_t)blockIdx.x * 128;
  const int jbase = blockIdx.y * CHUNK;

  const int srow = tid >> 2;        // staging: 0..127
  const int skq = (tid & 3) * 8;    // staging k offset (elements): 0,8,16,24

  // ---- phase 1: split A (z rows) into register fragments, full K ----
  bf16x8 afh[2][8], afl[2][8];
#pragma unroll
  for (int ks = 0; ks < 8; ++ks) {
    __syncthreads();
    {
      const float* src = z + (row0 + srow) * (size_t)D_DIM + ks * 32 + skq;
      float4 v0 = *reinterpret_cast<const float4*>(src);
      float4 v1 = *reinterpret_cast<const float4*>(src + 4);
      float s[8] = {v0.x, v0.y, v0.z, v0.w, v1.x, v1.y, v1.z, v1.w};
      short h[8], l[8];
#pragma unroll
      for (int i = 0; i < 8; ++i) {
        h[i] = f2bf(s[i]);
        l[i] = f2bf(s[i] - bf2f(h[i]));
      }
      *reinterpret_cast<bf16x4*>(&th[0][srow * LDK + skq]) = (bf16x4){h[0], h[1], h[2], h[3]};
      *reinterpret_cast<bf16x4*>(&th[0][srow * LDK + skq + 4]) = (bf16x4){h[4], h[5], h[6], h[7]};
      *reinterpret_cast<bf16x4*>(&tl[0][srow * LDK + skq]) = (bf16x4){l[0], l[1], l[2], l[3]};
      *reinterpret_cast<bf16x4*>(&tl[0][srow * LDK + skq + 4]) = (bf16x4){l[4], l[5], l[6], l[7]};
    }
    __syncthreads();
#pragma unroll
    for (int rt = 0; rt < 2; ++rt) {
      int r = wr * 32 + rt * 16 + lrow;
      afh[rt][ks] = *reinterpret_cast<const bf16x8*>(&th[0][r * LDK + lq * 8]);
      afl[rt][ks] = *reinterpret_cast<const bf16x8*>(&tl[0][r * LDK + lq * 8]);
    }
  }

  // per-lane row slots: slot s=rt*4+rr -> row row0 + wr*32 + rt*16 + lq*4 + rr
  float zrow2[8];
#pragma unroll
  for (int rt = 0; rt < 2; ++rt)
#pragma unroll
    for (int rr = 0; rr < 4; ++rr)
      zrow2[rt * 4 + rr] = zzf[row0 + wr * 32 + rt * 16 + lq * 4 + rr];

  float bv1[8], bv2[8];
  int bj1[8];
#pragma unroll
  for (int s = 0; s < 8; ++s) { bv1[s] = INFINITY; bv2[s] = INFINITY; bj1[s] = 0; }

  bf16x8 ph, pl;
  float4 pf0, pf1;

  // ---- prologue: slice 0 -> buf[0]; slice 1 -> regs (in flight) ----
  if (PRESPLIT) {
    ph = *reinterpret_cast<const bf16x8*>(emb_h + (size_t)(jbase + srow) * D_DIM + skq);
    pl = *reinterpret_cast<const bf16x8*>(emb_l + (size_t)(jbase + srow) * D_DIM + skq);
  } else {
    const float* src = emb + (size_t)(jbase + srow) * D_DIM + skq;
    pf0 = *reinterpret_cast<const float4*>(src);
    pf1 = *reinterpret_cast<const float4*>(src + 4);
  }
  __syncthreads();   // phase-1 reads of th[0]/tl[0] complete (full drain, once)
  if (PRESPLIT) {
    *reinterpret_cast<bf16x8*>(&th[0][srow * LDK + skq]) = ph;
    *reinterpret_cast<bf16x8*>(&tl[0][srow * LDK + skq]) = pl;
    ph = *reinterpret_cast<const bf16x8*>(emb_h + (size_t)(jbase + srow) * D_DIM + 32 + skq);
    pl = *reinterpret_cast<const bf16x8*>(emb_l + (size_t)(jbase + srow) * D_DIM + 32 + skq);
  } else {
    float s[8] = {pf0.x, pf0.y, pf0.z, pf0.w, pf1.x, pf1.y, pf1.z, pf1.w};
    short h[8], l[8];
#pragma unroll
    for (int i = 0; i < 8; ++i) {
      h[i] = f2bf(s[i]);
      l[i] = f2bf(s[i] - bf2f(h[i]));
    }
    *reinterpret_cast<bf16x4*>(&th[0][srow * LDK + skq]) = (bf16x4){h[0], h[1], h[2], h[3]};
    *reinterpret_cast<bf16x4*>(&th[0][srow * LDK + skq + 4]) = (bf16x4){h[4], h[5], h[6], h[7]};
    *reinterpret_cast<bf16x4*>(&tl[0][srow * LDK + skq]) = (bf16x4){l[0], l[1], l[2], l[3]};
    *reinterpret_cast<bf16x4*>(&tl[0][srow * LDK + skq + 4]) = (bf16x4){l[4], l[5], l[6], l[7]};
    const float* src = emb + (size_t)(jbase + srow) * D_DIM + 32 + skq;
    pf0 = *reinterpret_cast<const float4*>(src);
    pf1 = *reinterpret_cast<const float4*>(src + 4);
  }
  asm volatile("s_waitcnt lgkmcnt(0)" ::: "memory");
  __builtin_amdgcn_s_barrier();
  asm volatile("" ::: "memory");

  // ---- main loop: buf[ks&1] holds slice sl, regs hold slice sl+1 ----
  for (int jt0 = jbase; jt0 < jbase + CHUNK; jt0 += 128) {
    float enq[4];
#pragma unroll
    for (int ct = 0; ct < 4; ++ct) enq[ct] = enf[jt0 + wc * 64 + ct * 16 + lrow];

    f32x4 acc[2][4];
#pragma unroll
    for (int rt = 0; rt < 2; ++rt)
#pragma unroll
      for (int ct = 0; ct < 4; ++ct) acc[rt][ct] = (f32x4){0.f, 0.f, 0.f, 0.f};

#pragma unroll
    for (int ks = 0; ks < 8; ++ks) {
      const int p = ks & 1;
      bf16x8 bfh[4];
#pragma unroll
      for (int ct = 0; ct < 4; ++ct) {
        int c = wc * 64 + ct * 16 + lrow;
        bfh[ct] = *reinterpret_cast<const bf16x8*>(&th[p][c * LDK + lq * 8]);
      }
      __builtin_amdgcn_s_setprio(1);
#pragma unroll
      for (int rt = 0; rt < 2; ++rt)
#pragma unroll
        for (int ct = 0; ct < 4; ++ct) {
          acc[rt][ct] = __builtin_amdgcn_mfma_f32_16x16x32_bf16(
              afl[rt][ks], bfh[ct], acc[rt][ct], 0, 0, 0);   // zl*eh
          acc[rt][ct] = __builtin_amdgcn_mfma_f32_16x16x32_bf16(
              afh[rt][ks], bfh[ct], acc[rt][ct], 0, 0, 0);   // zh*eh
        }
      __builtin_amdgcn_s_setprio(0);

      // stage slice sl+1 (regs) into buf[p^1]; counted vmcnt inserted by compiler
      if (PRESPLIT) {
        *reinterpret_cast<bf16x8*>(&th[p ^ 1][srow * LDK + skq]) = ph;
        *reinterpret_cast<bf16x8*>(&tl[p ^ 1][srow * LDK + skq]) = pl;
      } else {
        float s[8] = {pf0.x, pf0.y, pf0.z, pf0.w, pf1.x, pf1.y, pf1.z, pf1.w};
        short h[8], l[8];
#pragma unroll
        for (int i = 0; i < 8; ++i) {
          h[i] = f2bf(s[i]);
          l[i] = f2bf(s[i] - bf2f(h[i]));
        }
        *reinterpret_cast<bf16x4*>(&th[p ^ 1][srow * LDK + skq]) = (bf16x4){h[0], h[1], h[2], h[3]};
        *reinterpret_cast<bf16x4*>(&th[p ^ 1][srow * LDK + skq + 4]) = (bf16x4){h[4], h[5], h[6], h[7]};
        *reinterpret_cast<bf16x4*>(&tl[p ^ 1][srow * LDK + skq]) = (bf16x4){l[0], l[1], l[2], l[3]};
        *reinterpret_cast<bf16x4*>(&tl[p ^ 1][srow * LDK + skq + 4]) = (bf16x4){l[4], l[5], l[6], l[7]};
      }
      // issue prefetch of slice sl+2 (stays in flight across the raw barrier)
      {
        int sl = ((jt0 - jbase) >> 4) + ks + 2;        // slices of 128rows x 32k
        if (sl > CHUNK / 16 - 1) sl = CHUNK / 16 - 1;
        const size_t off = ((size_t)(jbase + (sl >> 3) * 128 + srow)) * D_DIM
                         + (sl & 7) * 32 + skq;
        if (PRESPLIT) {
          ph = *reinterpret_cast<const bf16x8*>(emb_h + off);
          pl = *reinterpret_cast<const bf16x8*>(emb_l + off);
        } else {
          pf0 = *reinterpret_cast<const float4*>(emb + off);
          pf1 = *reinterpret_cast<const float4*>(emb + off + 4);
        }
      }

      bf16x8 bfl[4];
#pragma unroll
      for (int ct = 0; ct < 4; ++ct) {
        int c = wc * 64 + ct * 16 + lrow;
        bfl[ct] = *reinterpret_cast<const bf16x8*>(&tl[p][c * LDK + lq * 8]);
      }
      __builtin_amdgcn_s_setprio(1);
#pragma unroll
      for (int rt = 0; rt < 2; ++rt)
#pragma unroll
        for (int ct = 0; ct < 4; ++ct)
          acc[rt][ct] = __builtin_amdgcn_mfma_f32_16x16x32_bf16(
              afh[rt][ks], bfl[ct], acc[rt][ct], 0, 0, 0);   // zh*el
      __builtin_amdgcn_s_setprio(0);

      asm volatile("s_waitcnt lgkmcnt(0)" ::: "memory");
      __builtin_amdgcn_s_barrier();
      asm volatile("" ::: "memory");
    }

    // epilogue: reference f32 chain; ascending order + strict < -> lowest index
#pragma unroll
    for (int ct = 0; ct < 4; ++ct) {
      int gj = jt0 + wc * 64 + ct * 16 + lrow;
      float ef = enq[ct];
#pragma unroll
      for (int rt = 0; rt < 2; ++rt)
#pragma unroll
        for (int rr = 0; rr < 4; ++rr) {
          int s = rt * 4 + rr;
          float t = zrow2[s] - 2.0f * acc[rt][ct][rr];
          float dv = t + ef;
          bj1[s] = (dv < bv1[s]) ? gj : bj1[s];
          bv2[s] = fminf(bv2[s], fmaxf(dv, bv1[s]));
          bv1[s] = fminf(bv1[s], dv);
        }
    }
  }

  // reduce top-2 across the 16 code-lanes (lrow) of each lane quarter
#pragma unroll
  for (int m = 1; m < 16; m <<= 1) {
#pragma unroll
    for (int s = 0; s < 8; ++s) {
      float ov1 = __shfl_xor(bv1[s], m, 16);
      float ov2 = __shfl_xor(bv2[s], m, 16);
      int oj1 = __shfl_xor(bj1[s], m, 16);
      if (ov1 < bv1[s] || (ov1 == bv1[s] && oj1 < bj1[s])) {
        bv2[s] = fminf(bv1[s], ov2);
        bv1[s] = ov1; bj1[s] = oj1;
      } else {
        bv2[s] = fminf(bv2[s], ov1);
      }
    }
  }
  if (lrow == 0) {
#pragma unroll
    for (int s = 0; s < 8; ++s) {
      size_t grow = row0 + wr * 32 + (s >> 2) * 16 + lq * 4 + (s & 3);
      size_t o = (size_t)(blockIdx.y * 2 + wc) * M_TOT + grow;
      pv1[o] = bv1[s]; pv2[o] = bv2[s]; pj1[o] = bj1[s];
    }
  }
}

// ---------------------------------------------------------------------------
// Kernel 3: fold MSPLIT partial top-2s per row; flag ambiguous rows (exporting
// v1 and zeroing the row's candidate counter for the refine scan).
__global__ __launch_bounds__(256) void vq_merge(
    const float* __restrict__ pv1, const float* __restrict__ pv2,
    const int* __restrict__ pj1, int* __restrict__ idx_ws,
    int* __restrict__ cnt, int* __restrict__ flagged,
    float* __restrict__ flagv1, int* __restrict__ gnc) {
  int m = blockIdx.x * 256 + threadIdx.x;
  if (m >= M_TOT) return;
  float v1 = INFINITY, v2 = INFINITY;
  int j1 = 0;
#pragma unroll
  for (int s = 0; s < MSPLIT; ++s) {
    float a1 = pv1[(size_t)s * M_TOT + m];
    float a2 = pv2[(size_t)s * M_TOT + m];
    int aj = pj1[(size_t)s * M_TOT + m];
    if (a1 < v1 || (a1 == v1 && aj < j1)) {
      v2 = fminf(v1, a2); v1 = a1; j1 = aj;
    } else {
      v2 = fminf(v2, a1);
    }
  }
  idx_ws[m] = j1;
  float u = ldexpf(1.0f, ilogbf(v2) - 23);
  if (v2 - v1 <= 2.0f * u + 1e-5f) {
    int p = atomicAdd(cnt, 1);
    flagged[p] = m;
    flagv1[p] = v1;
    gnc[p] = 0;
  }
}

// ---------------------------------------------------------------------------
// Kernel 4a: refine candidate scan — MFMA chunked. Rows: 128 flagged rows per
// blockIdx.x (indirect gather); codes: 1024-code chunk per blockIdx.y (x8).
// Same pipelined split-bf16 structure as kernel 2; epilogue appends codes with
// dv <= thr (= v1 + 4u + 2.5e-5, covers mfma+scan error, proof as r9) to
// global per-row candidate lists.
#define RSPLIT 8
#define RCHUNK (NE / RSPLIT)   // 1024
#define GCAP 16

template <int PRESPLIT>
__global__ __launch_bounds__(512, 2) void vq_refine_scan(
    const float* __restrict__ z, const float* __restrict__ emb,
    const short* __restrict__ emb_h, const short* __restrict__ emb_l,
    const float* __restrict__ zzf, const float* __restrict__ enf,
    const int* __restrict__ cnt, const int* __restrict__ flagged,
    const float* __restrict__ flagv1, int* __restrict__ gnc,
    int* __restrict__ gcj) {
  int n = *cnt;
  if (n > (int)M_TOT) n = (int)M_TOT;
  const int base = blockIdx.x * 128;
  if (base >= n) return;

  __shared__ short th[2][LSLICE];
  __shared__ short tl[2][LSLICE];
  __shared__ int rowm_s[128];
  __shared__ float thr_s[128];
  __shared__ float rzz_s[128];

  const int tid = threadIdx.x;
  const int lane = tid & 63;
  const int wave = tid >> 6;
  const int wr = wave >> 1;
  const int wc = wave & 1;
  const int lrow = lane & 15;
  const int lq = lane >> 4;
  const int cb = blockIdx.y * RCHUNK;

  const int srow = tid >> 2;
  const int skq = (tid & 3) * 8;

  if (tid < 128) {
    bool valid = (base + tid) < n;
    int m = valid ? flagged[base + tid] : flagged[base];
    rowm_s[tid] = m;
    rzz_s[tid] = zzf[m];
    if (valid) {
      float v1 = flagv1[base + tid];
      float u = ldexpf(1.0f, ilogbf(v1) - 23);
      thr_s[tid] = v1 + 4.0f * u + 2.5e-5f;
    } else {
      thr_s[tid] = -INFINITY;
    }
  }

  // ---- phase 1: split A (gathered z rows) into register fragments ----
  bf16x8 afh[2][8], afl[2][8];
#pragma unroll
  for (int ks = 0; ks < 8; ++ks) {
    __syncthreads();
    {
      const float* src = z + (size_t)rowm_s[srow] * D_DIM + ks * 32 + skq;
      float4 v0 = *reinterpret_cast<const float4*>(src);
      float4 v1 = *reinterpret_cast<const float4*>(src + 4);
      float s[8] = {v0.x, v0.y, v0.z, v0.w, v1.x, v1.y, v1.z, v1.w};
      short h[8], l[8];
#pragma unroll
      for (int i = 0; i < 8; ++i) {
        h[i] = f2bf(s[i]);
        l[i] = f2bf(s[i] - bf2f(h[i]));
      }
      *reinterpret_cast<bf16x4*>(&th[0][srow * LDK + skq]) = (bf16x4){h[0], h[1], h[2], h[3]};
      *reinterpret_cast<bf16x4*>(&th[0][srow * LDK + skq + 4]) = (bf16x4){h[4], h[5], h[6], h[7]};
      *reinterpret_cast<bf16x4*>(&tl[0][srow * LDK + skq]) = (bf16x4){l[0], l[1], l[2], l[3]};
      *reinterpret_cast<bf16x4*>(&tl[0][srow * LDK + skq + 4]) = (bf16x4){l[4], l[5], l[6], l[7]};
    }
    __syncthreads();
#pragma unroll
    for (int rt = 0; rt < 2; ++rt) {
      int r = wr * 32 + rt * 16 + lrow;
      afh[rt][ks] = *reinterpret_cast<const bf16x8*>(&th[0][r * LDK + lq * 8]);
      afl[rt][ks] = *reinterpret_cast<const bf16x8*>(&tl[0][r * LDK + lq * 8]);
    }
  }

  float zrow2[8], thr8[8];
  int rcix8[8];
#pragma unroll
  for (int rt = 0; rt < 2; ++rt)
#pragma unroll
    for (int rr = 0; rr < 4; ++rr) {
      int s = rt * 4 + rr;
      int lrloc = wr * 32 + rt * 16 + lq * 4 + rr;
      zrow2[s] = rzz_s[lrloc];
      thr8[s] = thr_s[lrloc];
      rcix8[s] = base + lrloc;
    }

  bf16x8 ph, pl;
  float4 pf0, pf1;

  // ---- prologue ----
  if (PRESPLIT) {
    ph = *reinterpret_cast<const bf16x8*>(emb_h + (size_t)(cb + srow) * D_DIM + skq);
    pl = *reinterpret_cast<const bf16x8*>(emb_l + (size_t)(cb + srow) * D_DIM + skq);
  } else {
    const float* src = emb + (size_t)(cb + srow) * D_DIM + skq;
    pf0 = *reinterpret_cast<const float4*>(src);
    pf1 = *reinterpret_cast<const float4*>(src + 4);
  }
  __syncthreads();
  if (PRESPLIT) {
    *reinterpret_cast<bf16x8*>(&th[0][srow * LDK + skq]) = ph;
    *reinterpret_cast<bf16x8*>(&tl[0][srow * LDK + skq]) = pl;
    ph = *reinterpret_cast<const bf16x8*>(emb_h + (size_t)(cb + srow) * D_DIM + 32 + skq);
    pl = *reinterpret_cast<const bf16x8*>(emb_l + (size_t)(cb + srow) * D_DIM + 32 + skq);
  } else {
    float s[8] = {pf0.x, pf0.y, pf0.z, pf0.w, pf1.x, pf1.y, pf1.z, pf1.w};
    short h[8], l[8];
#pragma unroll
    for (int i = 0; i < 8; ++i) {
      h[i] = f2bf(s[i]);
      l[i] = f2bf(s[i] - bf2f(h[i]));
    }
    *reinterpret_cast<bf16x4*>(&th[0][srow * LDK + skq]) = (bf16x4){h[0], h[1], h[2], h[3]};
    *reinterpret_cast<bf16x4*>(&th[0][srow * LDK + skq + 4]) = (bf16x4){h[4], h[5], h[6], h[7]};
    *reinterpret_cast<bf16x4*>(&tl[0][srow * LDK + skq]) = (bf16x4){l[0], l[1], l[2], l[3]};
    *reinterpret_cast<bf16x4*>(&tl[0][srow * LDK + skq + 4]) = (bf16x4){l[4], l[5], l[6], l[7]};
    const float* src = emb + (size_t)(cb + srow) * D_DIM + 32 + skq;
    pf0 = *reinterpret_cast<const float4*>(src);
    pf1 = *reinterpret_cast<const float4*>(src + 4);
  }
  asm volatile("s_waitcnt lgkmcnt(0)" ::: "memory");
  __builtin_amdgcn_s_barrier();
  asm volatile("" ::: "memory");

  // ---- main loop over 8 code tiles of 128 in this chunk ----
  for (int jt0 = cb; jt0 < cb + RCHUNK; jt0 += 128) {
    float enq[4];
#pragma unroll
    for (int ct = 0; ct < 4; ++ct) enq[ct] = enf[jt0 + wc * 64 + ct * 16 + lrow];

    f32x4 acc[2][4];
#pragma unroll
    for (int rt = 0; rt < 2; ++rt)
#pragma unroll
      for (int ct = 0; ct < 4; ++ct) acc[rt][ct] = (f32x4){0.f, 0.f, 0.f, 0.f};

#pragma unroll
    for (int ks = 0; ks < 8; ++ks) {
      const int p = ks & 1;
      bf16x8 bfh[4];
#pragma unroll
      for (int ct = 0; ct < 4; ++ct) {
        int c = wc * 64 + ct * 16 + lrow;
        bfh[ct] = *reinterpret_cast<const bf16x8*>(&th[p][c * LDK + lq * 8]);
      }
      __builtin_amdgcn_s_setprio(1);
#pragma unroll
      for (int rt = 0; rt < 2; ++rt)
#pragma unroll
        for (int ct = 0; ct < 4; ++ct) {
          acc[rt][ct] = __builtin_amdgcn_mfma_f32_16x16x32_bf16(
              afl[rt][ks], bfh[ct], acc[rt][ct], 0, 0, 0);
          acc[rt][ct] = __builtin_amdgcn_mfma_f32_16x16x32_bf16(
              afh[rt][ks], bfh[ct], acc[rt][ct], 0, 0, 0);
        }
      __builtin_amdgcn_s_setprio(0);

      if (PRESPLIT) {
        *reinterpret_cast<bf16x8*>(&th[p ^ 1][srow * LDK + skq]) = ph;
        *reinterpret_cast<bf16x8*>(&tl[p ^ 1][srow * LDK + skq]) = pl;
      } else {
        float s[8] = {pf0.x, pf0.y, pf0.z, pf0.w, pf1.x, pf1.y, pf1.z, pf1.w};
        short h[8], l[8];
#pragma unroll
        for (int i = 0; i < 8; ++i) {
          h[i] = f2bf(s[i]);
          l[i] = f2bf(s[i] - bf2f(h[i]));
        }
        *reinterpret_cast<bf16x4*>(&th[p ^ 1][srow * LDK + skq]) = (bf16x4){h[0], h[1], h[2], h[3]};
        *reinterpret_cast<bf16x4*>(&th[p ^ 1][srow * LDK + skq + 4]) = (bf16x4){h[4], h[5], h[6], h[7]};
        *reinterpret_cast<bf16x4*>(&tl[p ^ 1][srow * LDK + skq]) = (bf16x4){l[0], l[1], l[2], l[3]};
        *reinterpret_cast<bf16x4*>(&tl[p ^ 1][srow * LDK + skq + 4]) = (bf16x4){l[4], l[5], l[6], l[7]};
      }
      {
        int sl = ((jt0 - cb) >> 4) + ks + 2;
        if (sl > RCHUNK / 16 - 1) sl = RCHUNK / 16 - 1;
        const size_t off = ((size_t)(cb + (sl >> 3) * 128 + srow)) * D_DIM
                         + (sl & 7) * 32 + skq;
        if (PRESPLIT) {
          ph = *reinterpret_cast<const bf16x8*>(emb_h + off);
          pl = *reinterpret_cast<const bf16x8*>(emb_l + off);
        } else {
          pf0 = *reinterpret_cast<const float4*>(emb + off);
          pf1 = *reinterpret_cast<const float4*>(emb + off + 4);
        }
      }

      bf16x8 bfl[4];
#pragma unroll
      for (int ct = 0; ct < 4; ++ct) {
        int c = wc * 64 + ct * 16 + lrow;
        bfl[ct] = *reinterpret_cast<const bf16x8*>(&tl[p][c * LDK + lq * 8]);
      }
      __builtin_amdgcn_s_setprio(1);
#pragma unroll
      for (int rt = 0; rt < 2; ++rt)
#pragma unroll
        for (int ct = 0; ct < 4; ++ct)
          acc[rt][ct] = __builtin_amdgcn_mfma_f32_16x16x32_bf16(
              afh[rt][ks], bfl[ct], acc[rt][ct], 0, 0, 0);
      __builtin_amdgcn_s_setprio(0);

      asm volatile("s_waitcnt lgkmcnt(0)" ::: "memory");
      __builtin_amdgcn_s_barrier();
      asm volatile("" ::: "memory");
    }

    // epilogue: append candidates with dv <= thr to global per-row lists
#pragma unroll
    for (int ct = 0; ct < 4; ++ct) {
      int gj = jt0 + wc * 64 + ct * 16 + lrow;
      float ef = enq[ct];
#pragma unroll
      for (int rt = 0; rt < 2; ++rt)
#pragma unroll
        for (int rr = 0; rr < 4; ++rr) {
          int s = rt * 4 + rr;
          float t = zrow2[s] - 2.0f * acc[rt][ct][rr];
          float dv = t + ef;
          if (dv <= thr8[s]) {
            int p = atomicAdd(&gnc[rcix8[s]], 1);
            if (p < GCAP) gcj[rcix8[s] * GCAP + p] = gj;
          }
        }
    }
  }
}

// ---------------------------------------------------------------------------
// Kernel 4b: refine finish — exact f64 eval of each flagged row's candidates
// (reference f32 chain, lowest-index ties). Full f64 scan fallback if a
// candidate list overflowed GCAP (deterministic, ~never taken).
__global__ __launch_bounds__(256) void vq_refine_fin(
    const float* __restrict__ z, const float* __restrict__ emb,
    const float* __restrict__ zzf, const float* __restrict__ enf,
    int* __restrict__ idx_ws, const int* __restrict__ cnt,
    const int* __restrict__ flagged, const int* __restrict__ gnc,
    const int* __restrict__ gcj) {
  __shared__ float zs[D_DIM];
  __shared__ float cdv[GCAP];
  __shared__ float rv[256];
  __shared__ int rj[256];

  const int tid = threadIdx.x;
  int n = *cnt;
  if (n > (int)M_TOT) n = (int)M_TOT;

  for (int rc = blockIdx.x; rc < n; rc += gridDim.x) {
    int m = flagged[rc];
    __syncthreads();                       // protect zs reuse across rows
    zs[tid] = z[(size_t)m * D_DIM + tid];
    __syncthreads();
    int nc = gnc[rc];
    float rzz = zzf[m];

    if (nc >= 1 && nc <= GCAP) {
      if (tid < nc) {
        int j = gcj[rc * GCAP + tid];
        const float4* er = reinterpret_cast<const float4*>(emb + (size_t)j * D_DIM);
        double a = 0.0;
#pragma unroll 4
        for (int k4 = 0; k4 < D_DIM / 4; ++k4) {
          float4 ev = er[k4];
          float4 zv = *reinterpret_cast<const float4*>(&zs[k4 * 4]);
          a = fma((double)zv.x, (double)ev.x, a);
          a = fma((double)zv.y, (double)ev.y, a);
          a = fma((double)zv.z, (double)ev.z, a);
          a = fma((double)zv.w, (double)ev.w, a);
        }
        float zef = (float)a;              // correctly-rounded f32(ze)
        float t = rzz - 2.0f * zef;
        cdv[tid] = t + enf[j];
      }
      __syncthreads();
      if (tid == 0) {
        float bvv = INFINITY; int bjj = 0x7FFFFFFF;
        for (int c = 0; c < nc; ++c) {
          float dv = cdv[c]; int j = gcj[rc * GCAP + c];
          if (dv < bvv || (dv == bvv && j < bjj)) { bvv = dv; bjj = j; }
        }
        idx_ws[m] = bjj;
      }
    } else if (nc > GCAP) {
      // fallback: cooperative full exact scan
      float bvv = INFINITY; int bjj = 0;
      for (int j = tid; j < NE; j += 256) {
        const float4* er = reinterpret_cast<const float4*>(emb + (size_t)j * D_DIM);
        double a = 0.0;
        for (int k4 = 0; k4 < D_DIM / 4; ++k4) {
          float4 ev = er[k4];
          float4 zv = *reinterpret_cast<const float4*>(&zs[k4 * 4]);
          a = fma((double)zv.x, (double)ev.x, a);
          a = fma((double)zv.y, (double)ev.y, a);
          a = fma((double)zv.z, (double)ev.z, a);
          a = fma((double)zv.w, (double)ev.w, a);
        }
        float zef = (float)a;
        float t = rzz - 2.0f * zef;
        float dv = t + enf[j];
        if (dv < bvv) { bvv = dv; bjj = j; }   // j ascending
      }
      rv[tid] = bvv; rj[tid] = bjj;
      __syncthreads();
      for (int s = 128; s > 0; s >>= 1) {
        if (tid < s) {
          float ov = rv[tid + s]; int oj = rj[tid + s];
          if (ov < rv[tid] || (ov == rv[tid] && oj < rj[tid])) {
            rv[tid] = ov; rj[tid] = oj;
          }
        }
        __syncthreads();
      }
      if (tid == 0) idx_ws[m] = rj[0];
    }
    // nc == 0 impossible (main-pass winner always passes thr); keep idx_ws
  }
}

// ---------------------------------------------------------------------------
// Kernel 5: idx (as float), age reset, usage histogram — after refine.
__global__ __launch_bounds__(256) void vq_scatter(
    const int* __restrict__ idx_ws, float* __restrict__ out) {
  int m = blockIdx.x * 256 + threadIdx.x;
  if (m >= M_TOT) return;
  int j = idx_ws[m];
  out[O_IDX + m] = (float)j;
  out[O_AGE + j] = 0.0f;            // benign race: all write 0
  atomicAdd(&out[O_USAGE + j], 1.0f);
}

// ---------------------------------------------------------------------------
// Kernel 6: z_q_st = z + (q - z) (mimics ref rounding), loss accumulation
// (one atomic per block via LDS wave-partials).
__global__ __launch_bounds__(256) void vq_gather(
    const float* __restrict__ z, const float* __restrict__ emb,
    const int* __restrict__ idx_ws, float* __restrict__ out) {
  __shared__ float lsum[4];
  size_t e4 = (size_t)blockIdx.x * 256 + threadIdx.x;  // float4 index
  size_t m = e4 >> 6;       // / (D/4)
  int dq = (int)(e4 & 63);
  int j = idx_ws[m];
  float4 q = *reinterpret_cast<const float4*>(emb + (size_t)j * D_DIM + dq * 4);
  float4 zv = *reinterpret_cast<const float4*>(z + e4 * 4);
  float dx = q.x - zv.x, dy = q.y - zv.y, dz = q.z - zv.z, dw = q.w - zv.w;
  float4 o;
  o.x = zv.x + dx; o.y = zv.y + dy; o.z = zv.z + dz; o.w = zv.w + dw;
  *reinterpret_cast<float4*>(out + e4 * 4) = o;
  float ls = dx * dx + dy * dy + dz * dz + dw * dw;
#pragma unroll
  for (int off = 32; off > 0; off >>= 1) ls += __shfl_down(ls, off, 64);
  if ((threadIdx.x & 63) == 0) lsum[threadIdx.x >> 6] = ls;
  __syncthreads();
  if (threadIdx.x == 0)
    atomicAdd(out + O_LOSS,
              (lsum[0] + lsum[1] + lsum[2] + lsum[3]) * (1.25f / 8388608.f));
}

// ---------------------------------------------------------------------------
// ws layout (f32 slots): zzf[32768] | enf[8192] | idx_ws[32768] | cnt |
//   flagged[32768] | flagv1[32768] | gnc[32768] | gcj[32768*16] |
//   pv1[4*32768] | pv2[4*32768] | pj1[4*32768] |
//   emb_h[2M shorts] | emb_l[2M shorts]   (~12.7 MB)
extern "C" void kernel_launch(void* const* d_in, const int* in_sizes, int n_in,
                              void* d_out, int out_size, void* d_ws, size_t ws_size,
                              hipStream_t stream) {
  const float* z = (const float*)d_in[0];
  const float* emb = (const float*)d_in[1];
  const float* code_age = (const float*)d_in[2];
  const float* code_usage = (const float*)d_in[3];
  float* out = (float*)d_out;

  float* zzf = (float*)d_ws;
  float* enf = zzf + M_TOT;
  int* idx_ws = (int*)(enf + NE);
  int* cnt = idx_ws + M_TOT;
  int* flagged = cnt + 1;
  float* flagv1 = (float*)(flagged + M_TOT);
  int* gnc = (int*)(flagv1 + M_TOT);
  int* gcj = gnc + M_TOT;
  float* pv1 = (float*)(gcj + M_TOT * GCAP);
  float* pv2 = pv1 + MSPLIT * M_TOT;
  int* pj1 = (int*)(pv2 + MSPLIT * M_TOT);
  short* emb_h = (short*)(pj1 + MSPLIT * M_TOT);
  short* emb_l = emb_h + (size_t)NE * D_DIM;

  const size_t ws_need = (size_t)((char*)(emb_l + (size_t)NE * D_DIM) - (char*)d_ws);
  const bool presplit = ws_size >= ws_need;   // ws_size constant -> deterministic

  hipLaunchKernelGGL(vq_prep, dim3(M_TOT / 256), dim3(256), 0, stream,
                     z, emb, code_age, code_usage, out, zzf, enf, cnt);
  if (presplit) {
    hipLaunchKernelGGL(vq_split, dim3(NE * (D_DIM / 4) / 256), dim3(256), 0, stream,
                       emb, emb_h, emb_l);
    hipLaunchKernelGGL((vq_argmin_mfma<1>), dim3(M_TOT / 128, 2), dim3(512), 0, stream,
                       z, emb, emb_h, emb_l, zzf, enf, pv1, pv2, pj1);
  } else {
    hipLaunchKernelGGL((vq_argmin_mfma<0>), dim3(M_TOT / 128, 2), dim3(512), 0, stream,
                       z, emb, emb_h, emb_l, zzf, enf, pv1, pv2, pj1);
  }
  hipLaunchKernelGGL(vq_merge, dim3(M_TOT / 256), dim3(256), 0, stream,
                     pv1, pv2, pj1, idx_ws, cnt, flagged, flagv1, gnc);
  if (presplit) {
    hipLaunchKernelGGL((vq_refine_scan<1>), dim3(M_TOT / 128, RSPLIT), dim3(512), 0, stream,
                       z, emb, emb_h, emb_l, zzf, enf, cnt, flagged, flagv1, gnc, gcj);
  } else {
    hipLaunchKernelGGL((vq_refine_scan<0>), dim3(M_TOT / 128, RSPLIT), dim3(512), 0, stream,
                       z, emb, emb_h, emb_l, zzf, enf, cnt, flagged, flagv1, gnc, gcj);
  }
  hipLaunchKernelGGL(vq_refine_fin, dim3(256), dim3(256), 0, stream,
                     z, emb, zzf, enf, idx_ws, cnt, flagged, gnc, gcj);
  hipLaunchKernelGGL(vq_scatter, dim3(M_TOT / 256), dim3(256), 0, stream,
                     idx_ws, out);
  hipLaunchKernelGGL(vq_gather, dim3((M_TOT * (D_DIM / 4)) / 256), dim3(256), 0, stream,
                     z, emb, idx_ws, out);
}